// Round 10
// baseline (234.368 us; speedup 1.0000x reference)
//
#include <hip/hip_runtime.h>

typedef __attribute__((ext_vector_type(4))) float f32x4;
typedef __attribute__((ext_vector_type(8))) __bf16 bf16x8;
typedef __attribute__((ext_vector_type(4))) __bf16 bf16x4;

#define MFMA16(a, b, c) __builtin_amdgcn_mfma_f32_16x16x32_bf16((a), (b), (c), 0, 0, 0)

typedef const __attribute__((address_space(1))) void* gas1_t;
typedef __attribute__((address_space(3))) void* las3_t;
#define GLOAD16(gp, lp) __builtin_amdgcn_global_load_lds((gas1_t)(gp), (las3_t)(lp), 16, 0, 0)

__device__ __forceinline__ unsigned short bfbits(float f) {
  __bf16 b = (__bf16)f;
  return *reinterpret_cast<unsigned short*>(&b);
}

// ---- swizzled 8KB unit: logical [128 rows][64 B], phys = pair-row + slot-XOR ----
__device__ __forceinline__ int tile_addr(int row, int kb) {
  int s = (((row & 1) << 2) | (kb >> 4)) ^ ((row >> 1) & 7);
  return ((row >> 1) << 7) | (s << 4) | (kb & 15);
}
// inverse: phys p in [0,8192), 16B-aligned -> (row, kb)
__device__ __forceinline__ void tile_decode(int p, int& row, int& kb) {
  int pair = p >> 7;
  int sx = ((p >> 4) & 7) ^ (pair & 7);
  row = (pair << 1) | (sx >> 2);
  kb = (sx & 3) << 4;
}

// ---------------- prep: G -> Gb (bf16) + Gt (bf16 transposed) ----------------
__global__ __launch_bounds__(256)
void gprep(const float* __restrict__ g, __bf16* __restrict__ Gb, __bf16* __restrict__ Gt) {
  __shared__ __bf16 Lt[128 * 132];
  int rb = blockIdx.x >> 3, cb = blockIdx.x & 7;
  int tid = threadIdx.x;
  #pragma unroll
  for (int it = 0; it < 16; ++it) {
    int idx = it * 256 + tid;
    int r = idx >> 5, c4 = idx & 31;
    float4 v = *reinterpret_cast<const float4*>(g + (size_t)(rb * 128 + r) * 1024 + cb * 128 + c4 * 4);
    bf16x4 h;
    h[0] = (__bf16)v.x; h[1] = (__bf16)v.y; h[2] = (__bf16)v.z; h[3] = (__bf16)v.w;
    *reinterpret_cast<bf16x4*>(Gb + (size_t)(rb * 128 + r) * 1024 + cb * 128 + c4 * 4) = h;
    #pragma unroll
    for (int e = 0; e < 4; ++e) Lt[(c4 * 4 + e) * 132 + r] = h[e];
  }
  __syncthreads();
  #pragma unroll
  for (int it = 0; it < 8; ++it) {
    int idx = it * 256 + tid;
    int i = idx >> 4, ch = idx & 15;
    bf16x8 v;
    #pragma unroll
    for (int e = 0; e < 8; ++e) v[e] = Lt[i * 132 + ch * 8 + e];
    *reinterpret_cast<bf16x8*>(Gt + (size_t)(cb * 128 + i) * 1024 + rb * 128 + ch * 8) = v;
  }
}

// Wt[k][j][c]: k0 = W0 - W2, k1 = W1, k2 = 2*W2
__global__ void prep_w3(const float* __restrict__ w, __bf16* __restrict__ wt) {
  int tid = blockIdx.x * 256 + threadIdx.x;
  if (tid < 3072) {
    int k = tid >> 10, rem = tid & 1023, j = rem >> 5, c = rem & 31;
    float wk = w[k * 1024 + c * 32 + j];
    float v;
    if (k == 0)      v = wk - w[2 * 1024 + c * 32 + j];
    else if (k == 1) v = wk;
    else             v = 2.0f * wk;
    wt[tid] = (__bf16)v;
  }
}

// ---------------- G^2: C[h][i] = sum_k Gb[h][k] * Gt[i][k] ----------------
__global__ __launch_bounds__(256, 2)
void gsq(const __bf16* __restrict__ Gb, const __bf16* __restrict__ Gt,
         __bf16* __restrict__ G2b) {
  __shared__ char lds[32768];
  const int tid = threadIdx.x;
  const int lane = tid & 63, wid = tid >> 6;
  const int l15 = lane & 15, lg = lane >> 4;
  const int wr = wid >> 1, wc = wid & 1;
  const int hb = (blockIdx.x >> 3) * 128, ib = (blockIdx.x & 7) * 128;

  int r0, kb0, r1, kb1;
  tile_decode(tid * 16, r0, kb0);
  tile_decode(tid * 16 + 4096, r1, kb1);
  const char* A0 = (const char*)Gb + (size_t)hb * 2048;
  const char* B0 = (const char*)Gt + (size_t)ib * 2048;

  auto stage = [&](int buf, int kt) {
    char* base = lds + buf * 16384;
    size_t oA0 = (size_t)r0 * 2048 + kt * 64 + kb0;
    size_t oA1 = (size_t)r1 * 2048 + kt * 64 + kb1;
    GLOAD16(A0 + oA0, base + wid * 1024);
    GLOAD16(A0 + oA1, base + 4096 + wid * 1024);
    GLOAD16(B0 + oA0, base + 8192 + wid * 1024);
    GLOAD16(B0 + oA1, base + 12288 + wid * 1024);
  };

  const f32x4 zero = {0.f, 0.f, 0.f, 0.f};
  f32x4 acc[4][4];
  #pragma unroll
  for (int a = 0; a < 4; ++a)
    #pragma unroll
    for (int b = 0; b < 4; ++b) acc[a][b] = zero;

  stage(0, 0);
  __syncthreads();
  for (int kt = 0; kt < 32; ++kt) {
    int cur = kt & 1;
    if (kt < 31) stage(cur ^ 1, kt + 1);
    const char* A = lds + cur * 16384;
    const char* B = A + 8192;
    bf16x8 af[4], bf[4];
    #pragma unroll
    for (int i = 0; i < 4; ++i) {
      af[i] = *reinterpret_cast<const bf16x8*>(A + tile_addr(wr * 64 + i * 16 + l15, lg * 16));
      bf[i] = *reinterpret_cast<const bf16x8*>(B + tile_addr(wc * 64 + i * 16 + l15, lg * 16));
    }
    #pragma unroll
    for (int a = 0; a < 4; ++a)
      #pragma unroll
      for (int b = 0; b < 4; ++b) acc[a][b] = MFMA16(af[a], bf[b], acc[a][b]);
    __syncthreads();
  }
  #pragma unroll
  for (int a = 0; a < 4; ++a)
    #pragma unroll
    for (int b = 0; b < 4; ++b)
      #pragma unroll
      for (int q = 0; q < 4; ++q) {
        int h = hb + wr * 64 + a * 16 + lg * 4 + q;
        int i = ib + wc * 64 + b * 16 + l15;
        G2b[(size_t)h * 1024 + i] = (__bf16)acc[a][b][q];
      }
}

// ---------------- main: x-direct B (no X0t), 3-buffer counted-vmcnt K-loop ----------------
// Per K-step: {issue B(t+1) f32 reg-loads; 12 ds_read frags; stageA(t+2) gloads;
//   lgkm0; 32 MFMA; vmcnt(4) [retires A(t+1)+B(t+1)]; cvt+ds_write B(t+1); lgkm0; barrier}.
// B converted f32->bf16 in-kernel (bit-identical to old k0_transpose rounding).
__global__ __launch_bounds__(256, 2)
void cheb_main(const __bf16* __restrict__ Gb, const __bf16* __restrict__ G2b,
               const float* __restrict__ x, const __bf16* __restrict__ Wt,
               const float* __restrict__ bias, float* __restrict__ out)
{
  __shared__ char lds[73728];
  // K-loop: 3 buffers @0/24576/49152, each {A1 8K | A2 8K | B 8K (ds_write-fed)}
  // epilogue (reuse): X0tile @0 (32K, [128 n][256 B bf16]), b1 @32768, b2 @40960

  const int tid = threadIdx.x;
  const int lane = tid & 63, wid = tid >> 6;
  const int l15 = lane & 15, lg = lane >> 4;
  const int wr = wid >> 1, wc = wid & 1;

  const int ht = blockIdx.x & 7;        // XCD-resident G/G2 panel
  const int nt = blockIdx.x >> 3;

  int r0, kb0, r1, kb1;
  tile_decode(tid * 16, r0, kb0);
  tile_decode(tid * 16 + 4096, r1, kb1);

  const char* A1g = (const char*)Gb + (size_t)ht * 128 * 2048;
  const char* A2g = (const char*)G2b + (size_t)ht * 128 * 2048;
  const int widb = wid * 1024;

  auto stageA = [&](char* base, int kt) {
    size_t o0 = (size_t)r0 * 2048 + kt * 64 + kb0;
    size_t o1 = (size_t)r1 * 2048 + kt * 64 + kb1;
    GLOAD16(A1g + o0, base + widb);
    GLOAD16(A1g + o1, base + 4096 + widb);
    GLOAD16(A2g + o0, base + 8192 + widb);
    GLOAD16(A2g + o1, base + 12288 + widb);
  };

  // B direct from x: thread covers row rB = tid>>1, k-half hB = tid&1 (16 floats/step)
  const int rB = tid >> 1, hB = tid & 1;
  const int nB = nt * 128 + rB;
  const int bb = nB >> 11, tt = (nB >> 5) & 63, cc = nB & 31;
  const float4* xB = reinterpret_cast<const float4*>(
                         x + (size_t)((bb * 32 + cc) * 64 + tt) * 1024) + hB * 4;
  const int oBw0 = 16384 + tile_addr(rB, hB * 32);
  const int oBw1 = 16384 + tile_addr(rB, hB * 32 + 16);

  // per-thread frag offsets within a buffer
  const int lgk = lg * 16;
  int offA[4], offB[4];
  #pragma unroll
  for (int a = 0; a < 4; ++a) offA[a] = tile_addr(wr * 64 + a * 16 + l15, lgk);
  #pragma unroll
  for (int b = 0; b < 4; ++b) offB[b] = 16384 + tile_addr(wc * 64 + b * 16 + l15, lgk);

  const f32x4 zero = {0.f, 0.f, 0.f, 0.f};
  f32x4 acc1[4][4], acc2[4][4];
  #pragma unroll
  for (int a = 0; a < 4; ++a)
    #pragma unroll
    for (int b = 0; b < 4; ++b) { acc1[a][b] = zero; acc2[a][b] = zero; }

  char* p0 = lds;
  char* p1 = lds + 24576;
  char* p2 = lds + 49152;

  // prologue: B(0) loads first (oldest), then A(0), A(1); cvt waits B(0) only (vmcnt(8))
  {
    float4 v0 = xB[0], v1 = xB[1], v2 = xB[2], v3 = xB[3];
    stageA(p0, 0);
    stageA(p1, 1);
    bf16x8 w0, w1;
    w0[0] = (__bf16)v0.x; w0[1] = (__bf16)v0.y; w0[2] = (__bf16)v0.z; w0[3] = (__bf16)v0.w;
    w0[4] = (__bf16)v1.x; w0[5] = (__bf16)v1.y; w0[6] = (__bf16)v1.z; w0[7] = (__bf16)v1.w;
    w1[0] = (__bf16)v2.x; w1[1] = (__bf16)v2.y; w1[2] = (__bf16)v2.z; w1[3] = (__bf16)v2.w;
    w1[4] = (__bf16)v3.x; w1[5] = (__bf16)v3.y; w1[6] = (__bf16)v3.z; w1[7] = (__bf16)v3.w;
    *reinterpret_cast<bf16x8*>(p0 + oBw0) = w0;
    *reinterpret_cast<bf16x8*>(p0 + oBw1) = w1;
  }
  asm volatile("s_waitcnt vmcnt(4) lgkmcnt(0)" ::: "memory");   // A(0) in LDS; A(1) in flight
  __builtin_amdgcn_sched_barrier(0);
  __builtin_amdgcn_s_barrier();

  for (int t = 0; t < 32; ++t) {
    float4 v0, v1, v2, v3;
    if (t < 31) {                        // issue B(t+1) reg-loads early
      const float4* s = xB + (t + 1) * 8;
      v0 = s[0]; v1 = s[1]; v2 = s[2]; v3 = s[3];
    }
    bf16x8 a1[4], a2[4], bf[4];
    #pragma unroll
    for (int i = 0; i < 4; ++i) {
      a1[i] = *reinterpret_cast<const bf16x8*>(p0 + offA[i]);
      a2[i] = *reinterpret_cast<const bf16x8*>(p0 + 8192 + offA[i]);
      bf[i] = *reinterpret_cast<const bf16x8*>(p0 + offB[i]);
    }
    if (t < 30) stageA(p2, t + 2);
    asm volatile("s_waitcnt lgkmcnt(0)" ::: "memory");
    __builtin_amdgcn_sched_barrier(0);
    __builtin_amdgcn_s_setprio(1);
    #pragma unroll
    for (int a = 0; a < 4; ++a)
      #pragma unroll
      for (int b = 0; b < 4; ++b) {
        acc1[a][b] = MFMA16(a1[a], bf[b], acc1[a][b]);
        acc2[a][b] = MFMA16(a2[a], bf[b], acc2[a][b]);
      }
    __builtin_amdgcn_s_setprio(0);
    if (t < 30) {
      asm volatile("s_waitcnt vmcnt(4)" ::: "memory");   // retire A(t+1) + B(t+1)
    } else if (t == 30) {
      asm volatile("s_waitcnt vmcnt(0)" ::: "memory");
    }
    if (t < 31) {                        // cvt + ds_write B(t+1) -> p1
      bf16x8 w0, w1;
      w0[0] = (__bf16)v0.x; w0[1] = (__bf16)v0.y; w0[2] = (__bf16)v0.z; w0[3] = (__bf16)v0.w;
      w0[4] = (__bf16)v1.x; w0[5] = (__bf16)v1.y; w0[6] = (__bf16)v1.z; w0[7] = (__bf16)v1.w;
      w1[0] = (__bf16)v2.x; w1[1] = (__bf16)v2.y; w1[2] = (__bf16)v2.z; w1[3] = (__bf16)v2.w;
      w1[4] = (__bf16)v3.x; w1[5] = (__bf16)v3.y; w1[6] = (__bf16)v3.z; w1[7] = (__bf16)v3.w;
      *reinterpret_cast<bf16x8*>(p1 + oBw0) = w0;
      *reinterpret_cast<bf16x8*>(p1 + oBw1) = w1;
      asm volatile("s_waitcnt lgkmcnt(0)" ::: "memory");
      __builtin_amdgcn_sched_barrier(0);
      __builtin_amdgcn_s_barrier();
    }
    char* tp = p0; p0 = p1; p1 = p2; p2 = tp;
  }

  __syncthreads();

  // ---- epilogue (R4-verified structure; X0tile staged from x with in-kernel cvt) ----
  {
    const int rE = tid >> 1, hE = tid & 1;
    const int nE = nt * 128 + rE;
    const int b2 = nE >> 11, t2 = (nE >> 5) & 63, c2 = nE & 31;
    const float4* xE = reinterpret_cast<const float4*>(
        x + (size_t)((b2 * 32 + c2) * 64 + t2) * 1024 + ht * 128 + hE * 64);
    char* dst = lds + rE * 256 + hE * 128;
    #pragma unroll
    for (int m = 0; m < 8; ++m) {
      float4 u0 = xE[2 * m], u1 = xE[2 * m + 1];
      bf16x8 wv;
      wv[0] = (__bf16)u0.x; wv[1] = (__bf16)u0.y; wv[2] = (__bf16)u0.z; wv[3] = (__bf16)u0.w;
      wv[4] = (__bf16)u1.x; wv[5] = (__bf16)u1.y; wv[6] = (__bf16)u1.z; wv[7] = (__bf16)u1.w;
      *reinterpret_cast<bf16x8*>(dst + m * 16) = wv;
    }
  }

  bf16x8 wf[3][2];
  #pragma unroll
  for (int s = 0; s < 3; ++s)
    #pragma unroll
    for (int jf = 0; jf < 2; ++jf)
      wf[s][jf] = *reinterpret_cast<const bf16x8*>(Wt + s * 1024 + (jf * 16 + l15) * 32 + lg * 8);
  float bv[2] = {bias[l15], bias[16 + l15]};

  #pragma unroll
  for (int bt = 0; bt < 4; ++bt) {
    if (bt > 0) __syncthreads();              // prev bt's reads done before overwrite
    // bounce this bt's acc columns -> b1/b2 as [128 h][32 c] swizzled tiles
    if (wc == (bt >> 1)) {
      #pragma unroll
      for (int a = 0; a < 4; ++a)
        #pragma unroll
        for (int bsel = 0; bsel < 2; ++bsel) {
          int b = ((bt & 1) << 1) | bsel;
          int cb = (bsel * 16 + l15) * 2;
          #pragma unroll
          for (int q = 0; q < 4; ++q) {
            int h = wr * 64 + a * 16 + lg * 4 + q;
            *reinterpret_cast<unsigned short*>(lds + 32768 + tile_addr(h, cb)) = bfbits(acc1[a][b][q]);
            *reinterpret_cast<unsigned short*>(lds + 40960 + tile_addr(h, cb)) = bfbits(acc2[a][b][q]);
          }
        }
    }
    __syncthreads();

    // D[h][j] = bias + X0*(W0-W2) + Y1*W1 + Y2*(2W2); wave owns h-slice wid*32
    f32x4 D[2][2];
    #pragma unroll
    for (int mf = 0; mf < 2; ++mf) {
      D[mf][0] = (f32x4){bv[0], bv[0], bv[0], bv[0]};
      D[mf][1] = (f32x4){bv[1], bv[1], bv[1], bv[1]};
    }
    #pragma unroll
    for (int mf = 0; mf < 2; ++mf) {
      int hx = wid * 32 + mf * 16 + l15;
      bf16x8 s0;
      #pragma unroll
      for (int i2 = 0; i2 < 8; ++i2)
        ((unsigned short*)&s0)[i2] =
            *reinterpret_cast<const unsigned short*>(lds + (bt * 32 + lg * 8 + i2) * 256 + hx * 2);
      bf16x8 s1 = *reinterpret_cast<const bf16x8*>(lds + 32768 + tile_addr(hx, lg * 16));
      bf16x8 s2 = *reinterpret_cast<const bf16x8*>(lds + 40960 + tile_addr(hx, lg * 16));
      #pragma unroll
      for (int jf = 0; jf < 2; ++jf) {
        D[mf][jf] = MFMA16(s0, wf[0][jf], D[mf][jf]);
        D[mf][jf] = MFMA16(s1, wf[1][jf], D[mf][jf]);
        D[mf][jf] = MFMA16(s2, wf[2][jf], D[mf][jf]);
      }
    }
    size_t ob = (size_t)(nt * 4 + bt) * 32768 + (size_t)(ht * 128 + wid * 32) * 32;
    #pragma unroll
    for (int mf = 0; mf < 2; ++mf)
      #pragma unroll
      for (int jf = 0; jf < 2; ++jf)
        #pragma unroll
        for (int q = 0; q < 4; ++q)
          out[ob + (size_t)(mf * 16 + lg * 4 + q) * 32 + jf * 16 + l15] = D[mf][jf][q];
  }
}

// ---------------- fallback (R1, proven): used if ws too small ----------------
__device__ __forceinline__ int swz_f(int c, int i) {
  return (c << 10) + (i ^ ((c & 7) << 3));
}
__global__ void prep_w_f(const float* __restrict__ w, __bf16* __restrict__ wt) {
  int tid = blockIdx.x * 256 + threadIdx.x;
  if (tid < 3 * 32 * 32) {
    int k = tid >> 10, rem = tid & 1023;
    int j = rem >> 5, c = rem & 31;
    float s = (k == 1) ? 0.5f : 1.0f;
    wt[tid] = (__bf16)(w[(k * 32 + c) * 32 + j] * s);
  }
}
__global__ __launch_bounds__(512, 2)
void cheb_fused(const float* __restrict__ x, const __bf16* __restrict__ Gb,
                const __bf16* __restrict__ Wt, const float* __restrict__ bias,
                float* __restrict__ out)
{
  __shared__ __bf16 ldsX[32 * 1024];
  __shared__ __bf16 ldsY[32 * 1024];
  const int wg = blockIdx.x;
  const int b = wg >> 6, t = wg & 63;
  const int tid = threadIdx.x;
  const int lane = tid & 63;
  const int wid = tid >> 6;
  const int l15 = lane & 15;
  const int lg = lane >> 4;
  {
    const int c = tid >> 4;
    const int seg = tid & 15;
    const float* xr = x + (size_t)((b * 32 + c) * 64 + t) * 1024;
    #pragma unroll
    for (int g = 0; g < 8; ++g) {
      int i0 = g * 128 + seg * 8;
      float4 v0 = *reinterpret_cast<const float4*>(xr + i0);
      float4 v1 = *reinterpret_cast<const float4*>(xr + i0 + 4);
      bf16x8 h;
      h[0] = (__bf16)v0.x; h[1] = (__bf16)v0.y; h[2] = (__bf16)v0.z; h[3] = (__bf16)v0.w;
      h[4] = (__bf16)v1.x; h[5] = (__bf16)v1.y; h[6] = (__bf16)v1.z; h[7] = (__bf16)v1.w;
      *reinterpret_cast<bf16x8*>(&ldsX[swz_f(c, i0)]) = h;
    }
  }
  __syncthreads();
  const f32x4 zero = {0.f, 0.f, 0.f, 0.f};
  f32x4 acc[8][2];
  #pragma unroll
  for (int r = 0; r < 8; ++r) { acc[r][0] = zero; acc[r][1] = zero; }
  const __bf16* Ga = Gb + (size_t)(wid * 128 + l15) * 1024 + lg * 8;
  #pragma unroll 2
  for (int k = 0; k < 1024; k += 32) {
    bf16x8 bf0 = *reinterpret_cast<const bf16x8*>(&ldsX[swz_f(l15, k + lg * 8)]);
    bf16x8 bf1 = *reinterpret_cast<const bf16x8*>(&ldsX[swz_f(16 + l15, k + lg * 8)]);
    bf16x8 af[8];
    #pragma unroll
    for (int r = 0; r < 8; ++r)
      af[r] = *reinterpret_cast<const bf16x8*>(Ga + r * 16 * 1024 + k);
    #pragma unroll
    for (int r = 0; r < 8; ++r) {
      acc[r][0] = MFMA16(af[r], bf0, acc[r][0]);
      acc[r][1] = MFMA16(af[r], bf1, acc[r][1]);
    }
  }
  #pragma unroll
  for (int r = 0; r < 8; ++r) {
    int hb = wid * 128 + r * 16 + lg * 4;
    #pragma unroll
    for (int cf = 0; cf < 2; ++cf) {
      int c = cf * 16 + l15;
      bf16x4 p;
      #pragma unroll
      for (int q = 0; q < 4; ++q) p[q] = (__bf16)(2.0f * acc[r][cf][q]);
      *reinterpret_cast<bf16x4*>(&ldsY[swz_f(c, hb)]) = p;
    }
  }
  __syncthreads();
  #pragma unroll
  for (int r = 0; r < 8; ++r) {
    int hb = wid * 128 + r * 16 + lg * 4;
    #pragma unroll
    for (int cf = 0; cf < 2; ++cf) {
      int c = cf * 16 + l15;
      bf16x4 xv = *reinterpret_cast<const bf16x4*>(&ldsX[swz_f(c, hb)]);
      f32x4 a;
      #pragma unroll
      for (int q = 0; q < 4; ++q) a[q] = -(float)xv[q];
      acc[r][cf] = a;
    }
  }
  #pragma unroll 2
  for (int k = 0; k < 1024; k += 32) {
    bf16x8 bf0 = *reinterpret_cast<const bf16x8*>(&ldsY[swz_f(l15, k + lg * 8)]);
    bf16x8 bf1 = *reinterpret_cast<const bf16x8*>(&ldsY[swz_f(16 + l15, k + lg * 8)]);
    bf16x8 af[8];
    #pragma unroll
    for (int r = 0; r < 8; ++r)
      af[r] = *reinterpret_cast<const bf16x8*>(Ga + r * 16 * 1024 + k);
    #pragma unroll
    for (int r = 0; r < 8; ++r) {
      acc[r][0] = MFMA16(af[r], bf0, acc[r][0]);
      acc[r][1] = MFMA16(af[r], bf1, acc[r][1]);
    }
  }
  f32x4 oacc[8][2];
  {
    float b0 = bias[l15], b1 = bias[16 + l15];
    f32x4 v0 = {b0, b0, b0, b0}, v1 = {b1, b1, b1, b1};
    #pragma unroll
    for (int r = 0; r < 8; ++r) { oacc[r][0] = v0; oacc[r][1] = v1; }
  }
  auto contrib = [&](const __bf16* lds, const __bf16* wtk) {
    bf16x8 w0 = *reinterpret_cast<const bf16x8*>(wtk + l15 * 32 + lg * 8);
    bf16x8 w1 = *reinterpret_cast<const bf16x8*>(wtk + (16 + l15) * 32 + lg * 8);
    #pragma unroll
    for (int r = 0; r < 8; ++r) {
      int h = wid * 128 + r * 16 + l15;
      bf16x8 af;
      #pragma unroll
      for (int j = 0; j < 8; ++j) af[j] = lds[swz_f(lg * 8 + j, h)];
      oacc[r][0] = MFMA16(af, w0, oacc[r][0]);
      oacc[r][1] = MFMA16(af, w1, oacc[r][1]);
    }
  };
  contrib(ldsX, Wt);
  #pragma unroll
  for (int r = 0; r < 8; ++r) {
    int hb = wid * 128 + r * 16 + lg * 4;
    #pragma unroll
    for (int cf = 0; cf < 2; ++cf) {
      int c = cf * 16 + l15;
      bf16x4 p;
      #pragma unroll
      for (int q = 0; q < 4; ++q) p[q] = (__bf16)acc[r][cf][q];
      *reinterpret_cast<bf16x4*>(&ldsX[swz_f(c, hb)]) = p;
    }
  }
  contrib(ldsY, Wt + 1024);
  contrib(ldsX, Wt + 2048);
  float* ob = out + (size_t)wg * 32768;
  #pragma unroll
  for (int r = 0; r < 8; ++r) {
    int hb = wid * 128 + r * 16 + lg * 4;
    #pragma unroll
    for (int q = 0; q < 4; ++q) {
      ob[(hb + q) * 32 + l15] = oacc[r][0][q];
      ob[(hb + q) * 32 + 16 + l15] = oacc[r][1][q];
    }
  }
}

// ---------------- launch ----------------
extern "C" void kernel_launch(void* const* d_in, const int* in_sizes, int n_in,
                              void* d_out, int out_size, void* d_ws, size_t ws_size,
                              hipStream_t stream) {
  const float* x    = (const float*)d_in[0];
  const float* gso  = (const float*)d_in[1];
  const float* w    = (const float*)d_in[2];
  const float* bias = (const float*)d_in[3];
  float* out = (float*)d_out;

  char* ws = (char*)d_ws;
  const size_t MB = 1024 * 1024;
  __bf16* Gb  = (__bf16*)(ws);                // 2 MB
  __bf16* Gt  = (__bf16*)(ws + 2 * MB);       // 2 MB
  __bf16* G2b = (__bf16*)(ws + 4 * MB);       // 2 MB
  __bf16* Wt  = (__bf16*)(ws + 6 * MB);       // 8 KB
  const size_t need = 8 * MB;

  if (ws_size >= need) {
    gprep<<<64, 256, 0, stream>>>(gso, Gb, Gt);
    prep_w3<<<12, 256, 0, stream>>>(w, Wt);
    gsq<<<64, 256, 0, stream>>>(Gb, Gt, G2b);
    cheb_main<<<2048, 256, 0, stream>>>(Gb, G2b, x, Wt, bias, out);
  } else {
    __bf16* Wtf = (__bf16*)(ws + 6 * MB);
    gprep<<<64, 256, 0, stream>>>(gso, Gb, Gt);
    prep_w_f<<<12, 256, 0, stream>>>(w, Wtf);
    cheb_fused<<<1024, 512, 0, stream>>>(x, Gb, Wtf, bias, out);
  }
}

// Round 11
// 227.198 us; speedup vs baseline: 1.0316x; 1.0316x over previous
//
#include <hip/hip_runtime.h>

typedef __attribute__((ext_vector_type(4))) float f32x4;
typedef __attribute__((ext_vector_type(8))) __bf16 bf16x8;
typedef __attribute__((ext_vector_type(4))) __bf16 bf16x4;

#define MFMA16(a, b, c) __builtin_amdgcn_mfma_f32_16x16x32_bf16((a), (b), (c), 0, 0, 0)

typedef const __attribute__((address_space(1))) void* gas1_t;
typedef __attribute__((address_space(3))) void* las3_t;
#define GLOAD16(gp, lp) __builtin_amdgcn_global_load_lds((gas1_t)(gp), (las3_t)(lp), 16, 0, 0)

__device__ __forceinline__ unsigned short bfbits(float f) {
  __bf16 b = (__bf16)f;
  return *reinterpret_cast<unsigned short*>(&b);
}

// ---- swizzled 8KB unit: logical [128 rows][64 B], phys = pair-row + slot-XOR ----
__device__ __forceinline__ int tile_addr(int row, int kb) {
  int s = (((row & 1) << 2) | (kb >> 4)) ^ ((row >> 1) & 7);
  return ((row >> 1) << 7) | (s << 4) | (kb & 15);
}
// inverse: phys p in [0,8192), 16B-aligned -> (row, kb)
__device__ __forceinline__ void tile_decode(int p, int& row, int& kb) {
  int pair = p >> 7;
  int sx = ((p >> 4) & 7) ^ (pair & 7);
  row = (pair << 1) | (sx >> 2);
  kb = (sx & 3) << 4;
}

// ---------------- prep: G -> Gb (bf16) + Gt (bf16 transposed) ----------------
__global__ __launch_bounds__(256)
void gprep(const float* __restrict__ g, __bf16* __restrict__ Gb, __bf16* __restrict__ Gt) {
  __shared__ __bf16 Lt[128 * 132];
  int rb = blockIdx.x >> 3, cb = blockIdx.x & 7;
  int tid = threadIdx.x;
  #pragma unroll
  for (int it = 0; it < 16; ++it) {
    int idx = it * 256 + tid;
    int r = idx >> 5, c4 = idx & 31;
    float4 v = *reinterpret_cast<const float4*>(g + (size_t)(rb * 128 + r) * 1024 + cb * 128 + c4 * 4);
    bf16x4 h;
    h[0] = (__bf16)v.x; h[1] = (__bf16)v.y; h[2] = (__bf16)v.z; h[3] = (__bf16)v.w;
    *reinterpret_cast<bf16x4*>(Gb + (size_t)(rb * 128 + r) * 1024 + cb * 128 + c4 * 4) = h;
    #pragma unroll
    for (int e = 0; e < 4; ++e) Lt[(c4 * 4 + e) * 132 + r] = h[e];
  }
  __syncthreads();
  #pragma unroll
  for (int it = 0; it < 8; ++it) {
    int idx = it * 256 + tid;
    int i = idx >> 4, ch = idx & 15;
    bf16x8 v;
    #pragma unroll
    for (int e = 0; e < 8; ++e) v[e] = Lt[i * 132 + ch * 8 + e];
    *reinterpret_cast<bf16x8*>(Gt + (size_t)(cb * 128 + i) * 1024 + rb * 128 + ch * 8) = v;
  }
}

// Wt[k][j][c]: k0 = W0 - W2, k1 = W1, k2 = 2*W2
__global__ void prep_w3(const float* __restrict__ w, __bf16* __restrict__ wt) {
  int tid = blockIdx.x * 256 + threadIdx.x;
  if (tid < 3072) {
    int k = tid >> 10, rem = tid & 1023, j = rem >> 5, c = rem & 31;
    float wk = w[k * 1024 + c * 32 + j];
    float v;
    if (k == 0)      v = wk - w[2 * 1024 + c * 32 + j];
    else if (k == 1) v = wk;
    else             v = 2.0f * wk;
    wt[tid] = (__bf16)v;
  }
}

// ---------------- G^2: C[h][i] = sum_k Gb[h][k] * Gt[i][k] ----------------
__global__ __launch_bounds__(256, 2)
void gsq(const __bf16* __restrict__ Gb, const __bf16* __restrict__ Gt,
         __bf16* __restrict__ G2b) {
  __shared__ char lds[32768];
  const int tid = threadIdx.x;
  const int lane = tid & 63, wid = tid >> 6;
  const int l15 = lane & 15, lg = lane >> 4;
  const int wr = wid >> 1, wc = wid & 1;
  const int hb = (blockIdx.x >> 3) * 128, ib = (blockIdx.x & 7) * 128;

  int r0, kb0, r1, kb1;
  tile_decode(tid * 16, r0, kb0);
  tile_decode(tid * 16 + 4096, r1, kb1);
  const char* A0 = (const char*)Gb + (size_t)hb * 2048;
  const char* B0 = (const char*)Gt + (size_t)ib * 2048;

  auto stage = [&](int buf, int kt) {
    char* base = lds + buf * 16384;
    size_t oA0 = (size_t)r0 * 2048 + kt * 64 + kb0;
    size_t oA1 = (size_t)r1 * 2048 + kt * 64 + kb1;
    GLOAD16(A0 + oA0, base + wid * 1024);
    GLOAD16(A0 + oA1, base + 4096 + wid * 1024);
    GLOAD16(B0 + oA0, base + 8192 + wid * 1024);
    GLOAD16(B0 + oA1, base + 12288 + wid * 1024);
  };

  const f32x4 zero = {0.f, 0.f, 0.f, 0.f};
  f32x4 acc[4][4];
  #pragma unroll
  for (int a = 0; a < 4; ++a)
    #pragma unroll
    for (int b = 0; b < 4; ++b) acc[a][b] = zero;

  stage(0, 0);
  __syncthreads();
  for (int kt = 0; kt < 32; ++kt) {
    int cur = kt & 1;
    if (kt < 31) stage(cur ^ 1, kt + 1);
    const char* A = lds + cur * 16384;
    const char* B = A + 8192;
    bf16x8 af[4], bf[4];
    #pragma unroll
    for (int i = 0; i < 4; ++i) {
      af[i] = *reinterpret_cast<const bf16x8*>(A + tile_addr(wr * 64 + i * 16 + l15, lg * 16));
      bf[i] = *reinterpret_cast<const bf16x8*>(B + tile_addr(wc * 64 + i * 16 + l15, lg * 16));
    }
    #pragma unroll
    for (int a = 0; a < 4; ++a)
      #pragma unroll
      for (int b = 0; b < 4; ++b) acc[a][b] = MFMA16(af[a], bf[b], acc[a][b]);
    __syncthreads();
  }
  #pragma unroll
  for (int a = 0; a < 4; ++a)
    #pragma unroll
    for (int b = 0; b < 4; ++b)
      #pragma unroll
      for (int q = 0; q < 4; ++q) {
        int h = hb + wr * 64 + a * 16 + lg * 4 + q;
        int i = ib + wc * 64 + b * 16 + l15;
        G2b[(size_t)h * 1024 + i] = (__bf16)acc[a][b][q];
      }
}

// ---------------- main: x-direct B (coalesced), 3-buffer counted-vmcnt K-loop ----------------
// B staging geometry: 8 lanes/row x 16B = the row's full 128B step-chunk contiguous
// (100% cacheline use); each thread covers 4 rows (row = (tid>>3)+32j), 1 float4/row/step,
// ds_write 8B bf16x4 into the swizzled B region (dense 512B/instr, conflict-free).
__global__ __launch_bounds__(256, 2)
void cheb_main(const __bf16* __restrict__ Gb, const __bf16* __restrict__ G2b,
               const float* __restrict__ x, const __bf16* __restrict__ Wt,
               const float* __restrict__ bias, float* __restrict__ out)
{
  __shared__ char lds[73728];
  // K-loop: 3 buffers @0/24576/49152, each {A1 8K | A2 8K | B 8K (ds_write-fed)}
  // epilogue (reuse): X0tile @0 (32K, [128 n][256 B bf16]), b1 @32768, b2 @40960

  const int tid = threadIdx.x;
  const int lane = tid & 63, wid = tid >> 6;
  const int l15 = lane & 15, lg = lane >> 4;
  const int wr = wid >> 1, wc = wid & 1;

  const int ht = blockIdx.x & 7;        // XCD-resident G/G2 panel
  const int nt = blockIdx.x >> 3;

  int r0, kb0, r1, kb1;
  tile_decode(tid * 16, r0, kb0);
  tile_decode(tid * 16 + 4096, r1, kb1);

  const char* A1g = (const char*)Gb + (size_t)ht * 128 * 2048;
  const char* A2g = (const char*)G2b + (size_t)ht * 128 * 2048;
  const int widb = wid * 1024;

  auto stageA = [&](char* base, int kt) {
    size_t o0 = (size_t)r0 * 2048 + kt * 64 + kb0;
    size_t o1 = (size_t)r1 * 2048 + kt * 64 + kb1;
    GLOAD16(A1g + o0, base + widb);
    GLOAD16(A1g + o1, base + 4096 + widb);
    GLOAD16(A2g + o0, base + 8192 + widb);
    GLOAD16(A2g + o1, base + 12288 + widb);
  };

  // B direct from x: coalesced mapping (see header comment)
  const int rB8 = tid >> 3, sB = tid & 7;
  const float4* xB4[4];
  int oBw[4];
  #pragma unroll
  for (int j = 0; j < 4; ++j) {
    int row = rB8 + 32 * j;
    int nB = nt * 128 + row;
    int bb = nB >> 11, tt = (nB >> 5) & 63, cc = nB & 31;
    xB4[j] = reinterpret_cast<const float4*>(
                 x + (size_t)((bb * 32 + cc) * 64 + tt) * 1024) + sB;
    oBw[j] = 16384 + tile_addr(row, sB * 8);
  }

  // per-thread frag offsets within a buffer
  const int lgk = lg * 16;
  int offA[4], offB[4];
  #pragma unroll
  for (int a = 0; a < 4; ++a) offA[a] = tile_addr(wr * 64 + a * 16 + l15, lgk);
  #pragma unroll
  for (int b = 0; b < 4; ++b) offB[b] = 16384 + tile_addr(wc * 64 + b * 16 + l15, lgk);

  const f32x4 zero = {0.f, 0.f, 0.f, 0.f};
  f32x4 acc1[4][4], acc2[4][4];
  #pragma unroll
  for (int a = 0; a < 4; ++a)
    #pragma unroll
    for (int b = 0; b < 4; ++b) { acc1[a][b] = zero; acc2[a][b] = zero; }

  char* p0 = lds;
  char* p1 = lds + 24576;
  char* p2 = lds + 49152;

  // prologue: B(0) loads first (oldest), then A(0), A(1); cvt waits B(0) only
  {
    float4 v[4];
    #pragma unroll
    for (int j = 0; j < 4; ++j) v[j] = xB4[j][0];
    stageA(p0, 0);
    stageA(p1, 1);
    #pragma unroll
    for (int j = 0; j < 4; ++j) {
      bf16x4 pk;
      pk[0] = (__bf16)v[j].x; pk[1] = (__bf16)v[j].y;
      pk[2] = (__bf16)v[j].z; pk[3] = (__bf16)v[j].w;
      *reinterpret_cast<bf16x4*>(p0 + oBw[j]) = pk;
    }
  }
  asm volatile("s_waitcnt vmcnt(4) lgkmcnt(0)" ::: "memory");   // A(0) in LDS; A(1) in flight
  __builtin_amdgcn_sched_barrier(0);
  __builtin_amdgcn_s_barrier();

  for (int t = 0; t < 32; ++t) {
    float4 v[4];
    if (t < 31) {                        // issue B(t+1) reg-loads early (oldest this step)
      #pragma unroll
      for (int j = 0; j < 4; ++j) v[j] = xB4[j][(t + 1) * 8];
    }
    bf16x8 a1[4], a2[4], bf[4];
    #pragma unroll
    for (int i = 0; i < 4; ++i) {
      a1[i] = *reinterpret_cast<const bf16x8*>(p0 + offA[i]);
      a2[i] = *reinterpret_cast<const bf16x8*>(p0 + 8192 + offA[i]);
      bf[i] = *reinterpret_cast<const bf16x8*>(p0 + offB[i]);
    }
    if (t < 30) stageA(p2, t + 2);
    asm volatile("s_waitcnt lgkmcnt(0)" ::: "memory");
    __builtin_amdgcn_sched_barrier(0);
    __builtin_amdgcn_s_setprio(1);
    #pragma unroll
    for (int a = 0; a < 4; ++a)
      #pragma unroll
      for (int b = 0; b < 4; ++b) {
        acc1[a][b] = MFMA16(a1[a], bf[b], acc1[a][b]);
        acc2[a][b] = MFMA16(a2[a], bf[b], acc2[a][b]);
      }
    __builtin_amdgcn_s_setprio(0);
    if (t < 30) {
      asm volatile("s_waitcnt vmcnt(4)" ::: "memory");   // retire A(t+1) + B(t+1)
    } else if (t == 30) {
      asm volatile("s_waitcnt vmcnt(0)" ::: "memory");
    }
    if (t < 31) {                        // cvt + ds_write B(t+1) -> p1
      #pragma unroll
      for (int j = 0; j < 4; ++j) {
        bf16x4 pk;
        pk[0] = (__bf16)v[j].x; pk[1] = (__bf16)v[j].y;
        pk[2] = (__bf16)v[j].z; pk[3] = (__bf16)v[j].w;
        *reinterpret_cast<bf16x4*>(p1 + oBw[j]) = pk;
      }
      asm volatile("s_waitcnt lgkmcnt(0)" ::: "memory");
      __builtin_amdgcn_sched_barrier(0);
      __builtin_amdgcn_s_barrier();
    }
    char* tp = p0; p0 = p1; p1 = p2; p2 = tp;
  }

  __syncthreads();

  // ---- epilogue (R10-verified; X0tile staged from x with in-kernel cvt) ----
  {
    const int rE = tid >> 1, hE = tid & 1;
    const int nE = nt * 128 + rE;
    const int b2 = nE >> 11, t2 = (nE >> 5) & 63, c2 = nE & 31;
    const float4* xE = reinterpret_cast<const float4*>(
        x + (size_t)((b2 * 32 + c2) * 64 + t2) * 1024 + ht * 128 + hE * 64);
    char* dst = lds + rE * 256 + hE * 128;
    #pragma unroll
    for (int m = 0; m < 8; ++m) {
      float4 u0 = xE[2 * m], u1 = xE[2 * m + 1];
      bf16x8 wv;
      wv[0] = (__bf16)u0.x; wv[1] = (__bf16)u0.y; wv[2] = (__bf16)u0.z; wv[3] = (__bf16)u0.w;
      wv[4] = (__bf16)u1.x; wv[5] = (__bf16)u1.y; wv[6] = (__bf16)u1.z; wv[7] = (__bf16)u1.w;
      *reinterpret_cast<bf16x8*>(dst + m * 16) = wv;
    }
  }

  bf16x8 wf[3][2];
  #pragma unroll
  for (int s = 0; s < 3; ++s)
    #pragma unroll
    for (int jf = 0; jf < 2; ++jf)
      wf[s][jf] = *reinterpret_cast<const bf16x8*>(Wt + s * 1024 + (jf * 16 + l15) * 32 + lg * 8);
  float bv[2] = {bias[l15], bias[16 + l15]};

  #pragma unroll
  for (int bt = 0; bt < 4; ++bt) {
    if (bt > 0) __syncthreads();              // prev bt's reads done before overwrite
    // bounce this bt's acc columns -> b1/b2 as [128 h][32 c] swizzled tiles
    if (wc == (bt >> 1)) {
      #pragma unroll
      for (int a = 0; a < 4; ++a)
        #pragma unroll
        for (int bsel = 0; bsel < 2; ++bsel) {
          int b = ((bt & 1) << 1) | bsel;
          int cb = (bsel * 16 + l15) * 2;
          #pragma unroll
          for (int q = 0; q < 4; ++q) {
            int h = wr * 64 + a * 16 + lg * 4 + q;
            *reinterpret_cast<unsigned short*>(lds + 32768 + tile_addr(h, cb)) = bfbits(acc1[a][b][q]);
            *reinterpret_cast<unsigned short*>(lds + 40960 + tile_addr(h, cb)) = bfbits(acc2[a][b][q]);
          }
        }
    }
    __syncthreads();

    // D[h][j] = bias + X0*(W0-W2) + Y1*W1 + Y2*(2W2); wave owns h-slice wid*32
    f32x4 D[2][2];
    #pragma unroll
    for (int mf = 0; mf < 2; ++mf) {
      D[mf][0] = (f32x4){bv[0], bv[0], bv[0], bv[0]};
      D[mf][1] = (f32x4){bv[1], bv[1], bv[1], bv[1]};
    }
    #pragma unroll
    for (int mf = 0; mf < 2; ++mf) {
      int hx = wid * 32 + mf * 16 + l15;
      bf16x8 s0;
      #pragma unroll
      for (int i2 = 0; i2 < 8; ++i2)
        ((unsigned short*)&s0)[i2] =
            *reinterpret_cast<const unsigned short*>(lds + (bt * 32 + lg * 8 + i2) * 256 + hx * 2);
      bf16x8 s1 = *reinterpret_cast<const bf16x8*>(lds + 32768 + tile_addr(hx, lg * 16));
      bf16x8 s2 = *reinterpret_cast<const bf16x8*>(lds + 40960 + tile_addr(hx, lg * 16));
      #pragma unroll
      for (int jf = 0; jf < 2; ++jf) {
        D[mf][jf] = MFMA16(s0, wf[0][jf], D[mf][jf]);
        D[mf][jf] = MFMA16(s1, wf[1][jf], D[mf][jf]);
        D[mf][jf] = MFMA16(s2, wf[2][jf], D[mf][jf]);
      }
    }
    size_t ob = (size_t)(nt * 4 + bt) * 32768 + (size_t)(ht * 128 + wid * 32) * 32;
    #pragma unroll
    for (int mf = 0; mf < 2; ++mf)
      #pragma unroll
      for (int jf = 0; jf < 2; ++jf)
        #pragma unroll
        for (int q = 0; q < 4; ++q)
          out[ob + (size_t)(mf * 16 + lg * 4 + q) * 32 + jf * 16 + l15] = D[mf][jf][q];
  }
}

// ---------------- fallback (R1, proven): used if ws too small ----------------
__device__ __forceinline__ int swz_f(int c, int i) {
  return (c << 10) + (i ^ ((c & 7) << 3));
}
__global__ void prep_w_f(const float* __restrict__ w, __bf16* __restrict__ wt) {
  int tid = blockIdx.x * 256 + threadIdx.x;
  if (tid < 3 * 32 * 32) {
    int k = tid >> 10, rem = tid & 1023;
    int j = rem >> 5, c = rem & 31;
    float s = (k == 1) ? 0.5f : 1.0f;
    wt[tid] = (__bf16)(w[(k * 32 + c) * 32 + j] * s);
  }
}
__global__ __launch_bounds__(512, 2)
void cheb_fused(const float* __restrict__ x, const __bf16* __restrict__ Gb,
                const __bf16* __restrict__ Wt, const float* __restrict__ bias,
                float* __restrict__ out)
{
  __shared__ __bf16 ldsX[32 * 1024];
  __shared__ __bf16 ldsY[32 * 1024];
  const int wg = blockIdx.x;
  const int b = wg >> 6, t = wg & 63;
  const int tid = threadIdx.x;
  const int lane = tid & 63;
  const int wid = tid >> 6;
  const int l15 = lane & 15;
  const int lg = lane >> 4;
  {
    const int c = tid >> 4;
    const int seg = tid & 15;
    const float* xr = x + (size_t)((b * 32 + c) * 64 + t) * 1024;
    #pragma unroll
    for (int g = 0; g < 8; ++g) {
      int i0 = g * 128 + seg * 8;
      float4 v0 = *reinterpret_cast<const float4*>(xr + i0);
      float4 v1 = *reinterpret_cast<const float4*>(xr + i0 + 4);
      bf16x8 h;
      h[0] = (__bf16)v0.x; h[1] = (__bf16)v0.y; h[2] = (__bf16)v0.z; h[3] = (__bf16)v0.w;
      h[4] = (__bf16)v1.x; h[5] = (__bf16)v1.y; h[6] = (__bf16)v1.z; h[7] = (__bf16)v1.w;
      *reinterpret_cast<bf16x8*>(&ldsX[swz_f(c, i0)]) = h;
    }
  }
  __syncthreads();
  const f32x4 zero = {0.f, 0.f, 0.f, 0.f};
  f32x4 acc[8][2];
  #pragma unroll
  for (int r = 0; r < 8; ++r) { acc[r][0] = zero; acc[r][1] = zero; }
  const __bf16* Ga = Gb + (size_t)(wid * 128 + l15) * 1024 + lg * 8;
  #pragma unroll 2
  for (int k = 0; k < 1024; k += 32) {
    bf16x8 bf0 = *reinterpret_cast<const bf16x8*>(&ldsX[swz_f(l15, k + lg * 8)]);
    bf16x8 bf1 = *reinterpret_cast<const bf16x8*>(&ldsX[swz_f(16 + l15, k + lg * 8)]);
    bf16x8 af[8];
    #pragma unroll
    for (int r = 0; r < 8; ++r)
      af[r] = *reinterpret_cast<const bf16x8*>(Ga + r * 16 * 1024 + k);
    #pragma unroll
    for (int r = 0; r < 8; ++r) {
      acc[r][0] = MFMA16(af[r], bf0, acc[r][0]);
      acc[r][1] = MFMA16(af[r], bf1, acc[r][1]);
    }
  }
  #pragma unroll
  for (int r = 0; r < 8; ++r) {
    int hb = wid * 128 + r * 16 + lg * 4;
    #pragma unroll
    for (int cf = 0; cf < 2; ++cf) {
      int c = cf * 16 + l15;
      bf16x4 p;
      #pragma unroll
      for (int q = 0; q < 4; ++q) p[q] = (__bf16)(2.0f * acc[r][cf][q]);
      *reinterpret_cast<bf16x4*>(&ldsY[swz_f(c, hb)]) = p;
    }
  }
  __syncthreads();
  #pragma unroll
  for (int r = 0; r < 8; ++r) {
    int hb = wid * 128 + r * 16 + lg * 4;
    #pragma unroll
    for (int cf = 0; cf < 2; ++cf) {
      int c = cf * 16 + l15;
      bf16x4 xv = *reinterpret_cast<const bf16x4*>(&ldsX[swz_f(c, hb)]);
      f32x4 a;
      #pragma unroll
      for (int q = 0; q < 4; ++q) a[q] = -(float)xv[q];
      acc[r][cf] = a;
    }
  }
  #pragma unroll 2
  for (int k = 0; k < 1024; k += 32) {
    bf16x8 bf0 = *reinterpret_cast<const bf16x8*>(&ldsY[swz_f(l15, k + lg * 8)]);
    bf16x8 bf1 = *reinterpret_cast<const bf16x8*>(&ldsY[swz_f(16 + l15, k + lg * 8)]);
    bf16x8 af[8];
    #pragma unroll
    for (int r = 0; r < 8; ++r)
      af[r] = *reinterpret_cast<const bf16x8*>(Ga + r * 16 * 1024 + k);
    #pragma unroll
    for (int r = 0; r < 8; ++r) {
      acc[r][0] = MFMA16(af[r], bf0, acc[r][0]);
      acc[r][1] = MFMA16(af[r], bf1, acc[r][1]);
    }
  }
  f32x4 oacc[8][2];
  {
    float b0 = bias[l15], b1 = bias[16 + l15];
    f32x4 v0 = {b0, b0, b0, b0}, v1 = {b1, b1, b1, b1};
    #pragma unroll
    for (int r = 0; r < 8; ++r) { oacc[r][0] = v0; oacc[r][1] = v1; }
  }
  auto contrib = [&](const __bf16* lds, const __bf16* wtk) {
    bf16x8 w0 = *reinterpret_cast<const bf16x8*>(wtk + l15 * 32 + lg * 8);
    bf16x8 w1 = *reinterpret_cast<const bf16x8*>(wtk + (16 + l15) * 32 + lg * 8);
    #pragma unroll
    for (int r = 0; r < 8; ++r) {
      int h = wid * 128 + r * 16 + l15;
      bf16x8 af;
      #pragma unroll
      for (int j = 0; j < 8; ++j) af[j] = lds[swz_f(lg * 8 + j, h)];
      oacc[r][0] = MFMA16(af, w0, oacc[r][0]);
      oacc[r][1] = MFMA16(af, w1, oacc[r][1]);
    }
  };
  contrib(ldsX, Wt);
  #pragma unroll
  for (int r = 0; r < 8; ++r) {
    int hb = wid * 128 + r * 16 + lg * 4;
    #pragma unroll
    for (int cf = 0; cf < 2; ++cf) {
      int c = cf * 16 + l15;
      bf16x4 p;
      #pragma unroll
      for (int q = 0; q < 4; ++q) p[q] = (__bf16)acc[r][cf][q];
      *reinterpret_cast<bf16x4*>(&ldsX[swz_f(c, hb)]) = p;
    }
  }
  contrib(ldsY, Wt + 1024);
  contrib(ldsX, Wt + 2048);
  float* ob = out + (size_t)wg * 32768;
  #pragma unroll
  for (int r = 0; r < 8; ++r) {
    int hb = wid * 128 + r * 16 + lg * 4;
    #pragma unroll
    for (int q = 0; q < 4; ++q) {
      ob[(hb + q) * 32 + l15] = oacc[r][0][q];
      ob[(hb + q) * 32 + 16 + l15] = oacc[r][1][q];
    }
  }
}

// ---------------- launch ----------------
extern "C" void kernel_launch(void* const* d_in, const int* in_sizes, int n_in,
                              void* d_out, int out_size, void* d_ws, size_t ws_size,
                              hipStream_t stream) {
  const float* x    = (const float*)d_in[0];
  const float* gso  = (const float*)d_in[1];
  const float* w    = (const float*)d_in[2];
  const float* bias = (const float*)d_in[3];
  float* out = (float*)d_out;

  char* ws = (char*)d_ws;
  const size_t MB = 1024 * 1024;
  __bf16* Gb  = (__bf16*)(ws);                // 2 MB
  __bf16* Gt  = (__bf16*)(ws + 2 * MB);       // 2 MB
  __bf16* G2b = (__bf16*)(ws + 4 * MB);       // 2 MB
  __bf16* Wt  = (__bf16*)(ws + 6 * MB);       // 8 KB
  const size_t need = 8 * MB;

  if (ws_size >= need) {
    gprep<<<64, 256, 0, stream>>>(gso, Gb, Gt);
    prep_w3<<<12, 256, 0, stream>>>(w, Wt);
    gsq<<<64, 256, 0, stream>>>(Gb, Gt, G2b);
    cheb_main<<<2048, 256, 0, stream>>>(Gb, G2b, x, Wt, bias, out);
  } else {
    __bf16* Wtf = (__bf16*)(ws + 6 * MB);
    gprep<<<64, 256, 0, stream>>>(gso, Gb, Gt);
    prep_w_f<<<12, 256, 0, stream>>>(w, Wtf);
    cheb_fused<<<1024, 512, 0, stream>>>(x, Gb, Wtf, bias, out);
  }
}

// Round 12
// 211.728 us; speedup vs baseline: 1.1069x; 1.0731x over previous
//
#include <hip/hip_runtime.h>

typedef __attribute__((ext_vector_type(4))) float f32x4;
typedef __attribute__((ext_vector_type(8))) __bf16 bf16x8;
typedef __attribute__((ext_vector_type(4))) __bf16 bf16x4;

#define MFMA16(a, b, c) __builtin_amdgcn_mfma_f32_16x16x32_bf16((a), (b), (c), 0, 0, 0)

typedef const __attribute__((address_space(1))) void* gas1_t;
typedef __attribute__((address_space(3))) void* las3_t;
#define GLOAD16(gp, lp) __builtin_amdgcn_global_load_lds((gas1_t)(gp), (las3_t)(lp), 16, 0, 0)

__device__ __forceinline__ unsigned short bfbits(float f) {
  __bf16 b = (__bf16)f;
  return *reinterpret_cast<unsigned short*>(&b);
}

// ---- swizzled 8KB unit: logical [128 rows][64 B], phys = pair-row + slot-XOR ----
__device__ __forceinline__ int tile_addr(int row, int kb) {
  int s = (((row & 1) << 2) | (kb >> 4)) ^ ((row >> 1) & 7);
  return ((row >> 1) << 7) | (s << 4) | (kb & 15);
}
// inverse: phys p in [0,8192), 16B-aligned -> (row, kb)
__device__ __forceinline__ void tile_decode(int p, int& row, int& kb) {
  int pair = p >> 7;
  int sx = ((p >> 4) & 7) ^ (pair & 7);
  row = (pair << 1) | (sx >> 2);
  kb = (sx & 3) << 4;
}

// ---------------- prep: G -> Gb (bf16) + Gt (bf16 transposed) ----------------
__global__ __launch_bounds__(256)
void gprep(const float* __restrict__ g, __bf16* __restrict__ Gb, __bf16* __restrict__ Gt) {
  __shared__ __bf16 Lt[128 * 132];
  int rb = blockIdx.x >> 3, cb = blockIdx.x & 7;
  int tid = threadIdx.x;
  #pragma unroll
  for (int it = 0; it < 16; ++it) {
    int idx = it * 256 + tid;
    int r = idx >> 5, c4 = idx & 31;
    float4 v = *reinterpret_cast<const float4*>(g + (size_t)(rb * 128 + r) * 1024 + cb * 128 + c4 * 4);
    bf16x4 h;
    h[0] = (__bf16)v.x; h[1] = (__bf16)v.y; h[2] = (__bf16)v.z; h[3] = (__bf16)v.w;
    *reinterpret_cast<bf16x4*>(Gb + (size_t)(rb * 128 + r) * 1024 + cb * 128 + c4 * 4) = h;
    #pragma unroll
    for (int e = 0; e < 4; ++e) Lt[(c4 * 4 + e) * 132 + r] = h[e];
  }
  __syncthreads();
  #pragma unroll
  for (int it = 0; it < 8; ++it) {
    int idx = it * 256 + tid;
    int i = idx >> 4, ch = idx & 15;
    bf16x8 v;
    #pragma unroll
    for (int e = 0; e < 8; ++e) v[e] = Lt[i * 132 + ch * 8 + e];
    *reinterpret_cast<bf16x8*>(Gt + (size_t)(cb * 128 + i) * 1024 + rb * 128 + ch * 8) = v;
  }
}

// Wt[k][j][c]: k0 = W0 - W2, k1 = W1, k2 = 2*W2
__global__ void prep_w3(const float* __restrict__ w, __bf16* __restrict__ wt) {
  int tid = blockIdx.x * 256 + threadIdx.x;
  if (tid < 3072) {
    int k = tid >> 10, rem = tid & 1023, j = rem >> 5, c = rem & 31;
    float wk = w[k * 1024 + c * 32 + j];
    float v;
    if (k == 0)      v = wk - w[2 * 1024 + c * 32 + j];
    else if (k == 1) v = wk;
    else             v = 2.0f * wk;
    wt[tid] = (__bf16)v;
  }
}

// X0t[(b*64+t)*32 + c][i] = x[b][c][t][i]
__global__ __launch_bounds__(256) void k0_transpose(const float* __restrict__ x,
                                                    __bf16* __restrict__ X0t) {
  int n0 = blockIdx.x * 8;
  int tid = threadIdx.x;
  #pragma unroll
  for (int r = 0; r < 8; ++r) {
    int n = n0 + r;
    int b = n >> 11, t = (n >> 5) & 63, c = n & 31;
    const float* src = x + (size_t)((b * 32 + c) * 64 + t) * 1024;
    float4 v = *reinterpret_cast<const float4*>(&src[tid * 4]);
    bf16x4 p;
    p[0] = (__bf16)v.x; p[1] = (__bf16)v.y; p[2] = (__bf16)v.z; p[3] = (__bf16)v.w;
    *reinterpret_cast<bf16x4*>(&X0t[(size_t)n * 1024 + tid * 4]) = p;
  }
}

// ---------------- G^2: C[h][i] = sum_k Gb[h][k] * Gt[i][k] ----------------
__global__ __launch_bounds__(256, 2)
void gsq(const __bf16* __restrict__ Gb, const __bf16* __restrict__ Gt,
         __bf16* __restrict__ G2b) {
  __shared__ char lds[32768];
  const int tid = threadIdx.x;
  const int lane = tid & 63, wid = tid >> 6;
  const int l15 = lane & 15, lg = lane >> 4;
  const int wr = wid >> 1, wc = wid & 1;
  const int hb = (blockIdx.x >> 3) * 128, ib = (blockIdx.x & 7) * 128;

  int r0, kb0, r1, kb1;
  tile_decode(tid * 16, r0, kb0);
  tile_decode(tid * 16 + 4096, r1, kb1);
  const char* A0 = (const char*)Gb + (size_t)hb * 2048;
  const char* B0 = (const char*)Gt + (size_t)ib * 2048;

  auto stage = [&](int buf, int kt) {
    char* base = lds + buf * 16384;
    size_t oA0 = (size_t)r0 * 2048 + kt * 64 + kb0;
    size_t oA1 = (size_t)r1 * 2048 + kt * 64 + kb1;
    GLOAD16(A0 + oA0, base + wid * 1024);
    GLOAD16(A0 + oA1, base + 4096 + wid * 1024);
    GLOAD16(B0 + oA0, base + 8192 + wid * 1024);
    GLOAD16(B0 + oA1, base + 12288 + wid * 1024);
  };

  const f32x4 zero = {0.f, 0.f, 0.f, 0.f};
  f32x4 acc[4][4];
  #pragma unroll
  for (int a = 0; a < 4; ++a)
    #pragma unroll
    for (int b = 0; b < 4; ++b) acc[a][b] = zero;

  stage(0, 0);
  __syncthreads();
  for (int kt = 0; kt < 32; ++kt) {
    int cur = kt & 1;
    if (kt < 31) stage(cur ^ 1, kt + 1);
    const char* A = lds + cur * 16384;
    const char* B = A + 8192;
    bf16x8 af[4], bf[4];
    #pragma unroll
    for (int i = 0; i < 4; ++i) {
      af[i] = *reinterpret_cast<const bf16x8*>(A + tile_addr(wr * 64 + i * 16 + l15, lg * 16));
      bf[i] = *reinterpret_cast<const bf16x8*>(B + tile_addr(wc * 64 + i * 16 + l15, lg * 16));
    }
    #pragma unroll
    for (int a = 0; a < 4; ++a)
      #pragma unroll
      for (int b = 0; b < 4; ++b) acc[a][b] = MFMA16(af[a], bf[b], acc[a][b]);
    __syncthreads();
  }
  #pragma unroll
  for (int a = 0; a < 4; ++a)
    #pragma unroll
    for (int b = 0; b < 4; ++b)
      #pragma unroll
      for (int q = 0; q < 4; ++q) {
        int h = hb + wr * 64 + a * 16 + lg * 4 + q;
        int i = ib + wc * 64 + b * 16 + l15;
        G2b[(size_t)h * 1024 + i] = (__bf16)acc[a][b][q];
      }
}

// ---------------- main: R9 structure, WITHOUT the lgkmcnt(0) pin before MFMAs ----------------
// Per K-step: {12 ds_read frags; stage t+2 (6 gloads); [compiler-inserted fine-grained
// lgkmcnt interleaves MFMAs with read returns]; vmcnt(6); s_barrier}.
// Cross-wave safety: every ds_read result is consumed by an MFMA before the end barrier
// (compiler drains lgkm for those uses); sched_barrier(0) after s_barrier blocks hoisting.
__global__ __launch_bounds__(256, 2)
void cheb_main(const __bf16* __restrict__ Gb, const __bf16* __restrict__ G2b,
               const __bf16* __restrict__ X0t, const __bf16* __restrict__ Wt,
               const float* __restrict__ bias, float* __restrict__ out)
{
  __shared__ char lds[73728];
  // K-loop: 3 buffers @0/24576/49152, each {A1 8K | A2 8K | B 8K}
  // epilogue (reuse): X0tile @0 (32K), b1 @32768 (8K), b2 @40960 (8K)

  const int tid = threadIdx.x;
  const int lane = tid & 63, wid = tid >> 6;
  const int l15 = lane & 15, lg = lane >> 4;
  const int wr = wid >> 1, wc = wid & 1;

  const int ht = blockIdx.x & 7;        // XCD-resident G/G2 panel
  const int nt = blockIdx.x >> 3;

  int r0, kb0, r1, kb1;
  tile_decode(tid * 16, r0, kb0);
  tile_decode(tid * 16 + 4096, r1, kb1);

  const char* A1g = (const char*)Gb + (size_t)ht * 128 * 2048;
  const char* A2g = (const char*)G2b + (size_t)ht * 128 * 2048;
  const char* Bg  = (const char*)X0t + (size_t)nt * 128 * 2048;

  const int widb = wid * 1024;

  auto stage = [&](char* base, int kt) {
    size_t o0 = (size_t)r0 * 2048 + kt * 64 + kb0;
    size_t o1 = (size_t)r1 * 2048 + kt * 64 + kb1;
    GLOAD16(A1g + o0, base + widb);
    GLOAD16(A1g + o1, base + 4096 + widb);
    GLOAD16(A2g + o0, base + 8192 + widb);
    GLOAD16(A2g + o1, base + 12288 + widb);
    GLOAD16(Bg + o0, base + 16384 + widb);
    GLOAD16(Bg + o1, base + 20480 + widb);
  };

  // per-thread frag offsets within a buffer
  const int lgk = lg * 16;
  int offA[4], offB[4];
  #pragma unroll
  for (int a = 0; a < 4; ++a) offA[a] = tile_addr(wr * 64 + a * 16 + l15, lgk);
  #pragma unroll
  for (int b = 0; b < 4; ++b) offB[b] = 16384 + tile_addr(wc * 64 + b * 16 + l15, lgk);

  const f32x4 zero = {0.f, 0.f, 0.f, 0.f};
  f32x4 acc1[4][4], acc2[4][4];
  #pragma unroll
  for (int a = 0; a < 4; ++a)
    #pragma unroll
    for (int b = 0; b < 4; ++b) { acc1[a][b] = zero; acc2[a][b] = zero; }

  char* p0 = lds;
  char* p1 = lds + 24576;
  char* p2 = lds + 49152;

  // prologue: stage tiles 0,1; wait tile 0 only (6 of 12 outstanding)
  stage(p0, 0);
  stage(p1, 1);
  asm volatile("s_waitcnt vmcnt(6)" ::: "memory");
  __builtin_amdgcn_sched_barrier(0);
  __builtin_amdgcn_s_barrier();
  __builtin_amdgcn_sched_barrier(0);

  for (int t = 0; t < 32; ++t) {
    bf16x8 a1[4], a2[4], bf[4];
    #pragma unroll
    for (int i = 0; i < 4; ++i) {
      bf[i] = *reinterpret_cast<const bf16x8*>(p0 + offB[i]);
      a1[i] = *reinterpret_cast<const bf16x8*>(p0 + offA[i]);
      a2[i] = *reinterpret_cast<const bf16x8*>(p0 + 8192 + offA[i]);
    }
    if (t < 30) stage(p2, t + 2);
    // NO explicit lgkmcnt(0) here: the compiler inserts fine-grained per-use
    // lgkmcnt waits, overlapping early MFMAs with late ds_read returns.
    __builtin_amdgcn_s_setprio(1);
    #pragma unroll
    for (int a = 0; a < 4; ++a)
      #pragma unroll
      for (int b = 0; b < 4; ++b) {
        acc1[a][b] = MFMA16(a1[a], bf[b], acc1[a][b]);
        acc2[a][b] = MFMA16(a2[a], bf[b], acc2[a][b]);
      }
    __builtin_amdgcn_s_setprio(0);
    if (t < 30) {
      asm volatile("s_waitcnt vmcnt(6)" ::: "memory");
    } else if (t == 30) {
      asm volatile("s_waitcnt vmcnt(0)" ::: "memory");
    }
    if (t < 31) {
      __builtin_amdgcn_sched_barrier(0);
      __builtin_amdgcn_s_barrier();
      __builtin_amdgcn_sched_barrier(0);
    }
    char* tp = p0; p0 = p1; p1 = p2; p2 = tp;
  }

  __syncthreads();

  // ---- epilogue (R4/R9-verified 4-wave version) ----
  // stage X0tile: [128 n-rows][256 B of h-cols], linear, 32KB @0
  #pragma unroll
  for (int i = 0; i < 8; ++i) {
    int pbase = i * 4096 + widb;              // wave-uniform dest (HW adds lane*16)
    int pb = pbase + lane * 16;
    int prow = pb >> 8, pcol = pb & 255;
    GLOAD16((const char*)X0t + (size_t)(nt * 128 + prow) * 2048 + ht * 256 + pcol,
            lds + pbase);
  }

  bf16x8 wf[3][2];
  #pragma unroll
  for (int s = 0; s < 3; ++s)
    #pragma unroll
    for (int jf = 0; jf < 2; ++jf)
      wf[s][jf] = *reinterpret_cast<const bf16x8*>(Wt + s * 1024 + (jf * 16 + l15) * 32 + lg * 8);
  float bv[2] = {bias[l15], bias[16 + l15]};

  #pragma unroll
  for (int bt = 0; bt < 4; ++bt) {
    if (bt > 0) __syncthreads();              // prev bt's reads done before overwrite
    // bounce this bt's acc columns -> b1/b2 as [128 h][32 c] swizzled tiles
    if (wc == (bt >> 1)) {
      #pragma unroll
      for (int a = 0; a < 4; ++a)
        #pragma unroll
        for (int bsel = 0; bsel < 2; ++bsel) {
          int b = ((bt & 1) << 1) | bsel;
          int cb = (bsel * 16 + l15) * 2;
          #pragma unroll
          for (int q = 0; q < 4; ++q) {
            int h = wr * 64 + a * 16 + lg * 4 + q;
            *reinterpret_cast<unsigned short*>(lds + 32768 + tile_addr(h, cb)) = bfbits(acc1[a][b][q]);
            *reinterpret_cast<unsigned short*>(lds + 40960 + tile_addr(h, cb)) = bfbits(acc2[a][b][q]);
          }
        }
    }
    __syncthreads();

    // D[h][j] = bias + X0*(W0-W2) + Y1*W1 + Y2*(2W2); wave owns h-slice wid*32
    f32x4 D[2][2];
    #pragma unroll
    for (int mf = 0; mf < 2; ++mf) {
      D[mf][0] = (f32x4){bv[0], bv[0], bv[0], bv[0]};
      D[mf][1] = (f32x4){bv[1], bv[1], bv[1], bv[1]};
    }
    #pragma unroll
    for (int mf = 0; mf < 2; ++mf) {
      int hx = wid * 32 + mf * 16 + l15;
      bf16x8 s0;
      #pragma unroll
      for (int i2 = 0; i2 < 8; ++i2)
        ((unsigned short*)&s0)[i2] =
            *reinterpret_cast<const unsigned short*>(lds + (bt * 32 + lg * 8 + i2) * 256 + hx * 2);
      bf16x8 s1 = *reinterpret_cast<const bf16x8*>(lds + 32768 + tile_addr(hx, lg * 16));
      bf16x8 s2 = *reinterpret_cast<const bf16x8*>(lds + 40960 + tile_addr(hx, lg * 16));
      #pragma unroll
      for (int jf = 0; jf < 2; ++jf) {
        D[mf][jf] = MFMA16(s0, wf[0][jf], D[mf][jf]);
        D[mf][jf] = MFMA16(s1, wf[1][jf], D[mf][jf]);
        D[mf][jf] = MFMA16(s2, wf[2][jf], D[mf][jf]);
      }
    }
    size_t ob = (size_t)(nt * 4 + bt) * 32768 + (size_t)(ht * 128 + wid * 32) * 32;
    #pragma unroll
    for (int mf = 0; mf < 2; ++mf)
      #pragma unroll
      for (int jf = 0; jf < 2; ++jf)
        #pragma unroll
        for (int q = 0; q < 4; ++q)
          out[ob + (size_t)(mf * 16 + lg * 4 + q) * 32 + jf * 16 + l15] = D[mf][jf][q];
  }
}

// ---------------- fallback (R1, proven): used if ws too small ----------------
__device__ __forceinline__ int swz_f(int c, int i) {
  return (c << 10) + (i ^ ((c & 7) << 3));
}
__global__ void prep_w_f(const float* __restrict__ w, __bf16* __restrict__ wt) {
  int tid = blockIdx.x * 256 + threadIdx.x;
  if (tid < 3 * 32 * 32) {
    int k = tid >> 10, rem = tid & 1023;
    int j = rem >> 5, c = rem & 31;
    float s = (k == 1) ? 0.5f : 1.0f;
    wt[tid] = (__bf16)(w[(k * 32 + c) * 32 + j] * s);
  }
}
__global__ __launch_bounds__(512, 2)
void cheb_fused(const float* __restrict__ x, const __bf16* __restrict__ Gb,
                const __bf16* __restrict__ Wt, const float* __restrict__ bias,
                float* __restrict__ out)
{
  __shared__ __bf16 ldsX[32 * 1024];
  __shared__ __bf16 ldsY[32 * 1024];
  const int wg = blockIdx.x;
  const int b = wg >> 6, t = wg & 63;
  const int tid = threadIdx.x;
  const int lane = tid & 63;
  const int wid = tid >> 6;
  const int l15 = lane & 15;
  const int lg = lane >> 4;
  {
    const int c = tid >> 4;
    const int seg = tid & 15;
    const float* xr = x + (size_t)((b * 32 + c) * 64 + t) * 1024;
    #pragma unroll
    for (int g = 0; g < 8; ++g) {
      int i0 = g * 128 + seg * 8;
      float4 v0 = *reinterpret_cast<const float4*>(xr + i0);
      float4 v1 = *reinterpret_cast<const float4*>(xr + i0 + 4);
      bf16x8 h;
      h[0] = (__bf16)v0.x; h[1] = (__bf16)v0.y; h[2] = (__bf16)v0.z; h[3] = (__bf16)v0.w;
      h[4] = (__bf16)v1.x; h[5] = (__bf16)v1.y; h[6] = (__bf16)v1.z; h[7] = (__bf16)v1.w;
      *reinterpret_cast<bf16x8*>(&ldsX[swz_f(c, i0)]) = h;
    }
  }
  __syncthreads();
  const f32x4 zero = {0.f, 0.f, 0.f, 0.f};
  f32x4 acc[8][2];
  #pragma unroll
  for (int r = 0; r < 8; ++r) { acc[r][0] = zero; acc[r][1] = zero; }
  const __bf16* Ga = Gb + (size_t)(wid * 128 + l15) * 1024 + lg * 8;
  #pragma unroll 2
  for (int k = 0; k < 1024; k += 32) {
    bf16x8 bf0 = *reinterpret_cast<const bf16x8*>(&ldsX[swz_f(l15, k + lg * 8)]);
    bf16x8 bf1 = *reinterpret_cast<const bf16x8*>(&ldsX[swz_f(16 + l15, k + lg * 8)]);
    bf16x8 af[8];
    #pragma unroll
    for (int r = 0; r < 8; ++r)
      af[r] = *reinterpret_cast<const bf16x8*>(Ga + r * 16 * 1024 + k);
    #pragma unroll
    for (int r = 0; r < 8; ++r) {
      acc[r][0] = MFMA16(af[r], bf0, acc[r][0]);
      acc[r][1] = MFMA16(af[r], bf1, acc[r][1]);
    }
  }
  #pragma unroll
  for (int r = 0; r < 8; ++r) {
    int hb = wid * 128 + r * 16 + lg * 4;
    #pragma unroll
    for (int cf = 0; cf < 2; ++cf) {
      int c = cf * 16 + l15;
      bf16x4 p;
      #pragma unroll
      for (int q = 0; q < 4; ++q) p[q] = (__bf16)(2.0f * acc[r][cf][q]);
      *reinterpret_cast<bf16x4*>(&ldsY[swz_f(c, hb)]) = p;
    }
  }
  __syncthreads();
  #pragma unroll
  for (int r = 0; r < 8; ++r) {
    int hb = wid * 128 + r * 16 + lg * 4;
    #pragma unroll
    for (int cf = 0; cf < 2; ++cf) {
      int c = cf * 16 + l15;
      bf16x4 xv = *reinterpret_cast<const bf16x4*>(&ldsX[swz_f(c, hb)]);
      f32x4 a;
      #pragma unroll
      for (int q = 0; q < 4; ++q) a[q] = -(float)xv[q];
      acc[r][cf] = a;
    }
  }
  #pragma unroll 2
  for (int k = 0; k < 1024; k += 32) {
    bf16x8 bf0 = *reinterpret_cast<const bf16x8*>(&ldsY[swz_f(l15, k + lg * 8)]);
    bf16x8 bf1 = *reinterpret_cast<const bf16x8*>(&ldsY[swz_f(16 + l15, k + lg * 8)]);
    bf16x8 af[8];
    #pragma unroll
    for (int r = 0; r < 8; ++r)
      af[r] = *reinterpret_cast<const bf16x8*>(Ga + r * 16 * 1024 + k);
    #pragma unroll
    for (int r = 0; r < 8; ++r) {
      acc[r][0] = MFMA16(af[r], bf0, acc[r][0]);
      acc[r][1] = MFMA16(af[r], bf1, acc[r][1]);
    }
  }
  f32x4 oacc[8][2];
  {
    float b0 = bias[l15], b1 = bias[16 + l15];
    f32x4 v0 = {b0, b0, b0, b0}, v1 = {b1, b1, b1, b1};
    #pragma unroll
    for (int r = 0; r < 8; ++r) { oacc[r][0] = v0; oacc[r][1] = v1; }
  }
  auto contrib = [&](const __bf16* lds, const __bf16* wtk) {
    bf16x8 w0 = *reinterpret_cast<const bf16x8*>(wtk + l15 * 32 + lg * 8);
    bf16x8 w1 = *reinterpret_cast<const bf16x8*>(wtk + (16 + l15) * 32 + lg * 8);
    #pragma unroll
    for (int r = 0; r < 8; ++r) {
      int h = wid * 128 + r * 16 + l15;
      bf16x8 af;
      #pragma unroll
      for (int j = 0; j < 8; ++j) af[j] = lds[swz_f(lg * 8 + j, h)];
      oacc[r][0] = MFMA16(af, w0, oacc[r][0]);
      oacc[r][1] = MFMA16(af, w1, oacc[r][1]);
    }
  };
  contrib(ldsX, Wt);
  #pragma unroll
  for (int r = 0; r < 8; ++r) {
    int hb = wid * 128 + r * 16 + lg * 4;
    #pragma unroll
    for (int cf = 0; cf < 2; ++cf) {
      int c = cf * 16 + l15;
      bf16x4 p;
      #pragma unroll
      for (int q = 0; q < 4; ++q) p[q] = (__bf16)acc[r][cf][q];
      *reinterpret_cast<bf16x4*>(&ldsX[swz_f(c, hb)]) = p;
    }
  }
  contrib(ldsY, Wt + 1024);
  contrib(ldsX, Wt + 2048);
  float* ob = out + (size_t)wg * 32768;
  #pragma unroll
  for (int r = 0; r < 8; ++r) {
    int hb = wid * 128 + r * 16 + lg * 4;
    #pragma unroll
    for (int q = 0; q < 4; ++q) {
      ob[(hb + q) * 32 + l15] = oacc[r][0][q];
      ob[(hb + q) * 32 + 16 + l15] = oacc[r][1][q];
    }
  }
}

// ---------------- launch ----------------
extern "C" void kernel_launch(void* const* d_in, const int* in_sizes, int n_in,
                              void* d_out, int out_size, void* d_ws, size_t ws_size,
                              hipStream_t stream) {
  const float* x    = (const float*)d_in[0];
  const float* gso  = (const float*)d_in[1];
  const float* w    = (const float*)d_in[2];
  const float* bias = (const float*)d_in[3];
  float* out = (float*)d_out;

  char* ws = (char*)d_ws;
  const size_t MB = 1024 * 1024;
  __bf16* Gb  = (__bf16*)(ws);                // 2 MB
  __bf16* Gt  = (__bf16*)(ws + 2 * MB);       // 2 MB
  __bf16* G2b = (__bf16*)(ws + 4 * MB);       // 2 MB
  __bf16* Wt  = (__bf16*)(ws + 6 * MB);       // 8 KB
  __bf16* X0t = (__bf16*)(ws + 8 * MB);       // 64 MB
  const size_t need = 8 * MB + 64 * MB;

  if (ws_size >= need) {
    gprep<<<64, 256, 0, stream>>>(gso, Gb, Gt);
    prep_w3<<<12, 256, 0, stream>>>(w, Wt);
    k0_transpose<<<4096, 256, 0, stream>>>(x, X0t);
    gsq<<<64, 256, 0, stream>>>(Gb, Gt, G2b);
    cheb_main<<<2048, 256, 0, stream>>>(Gb, G2b, X0t, Wt, bias, out);
  } else {
    __bf16* Wtf = (__bf16*)(ws + 6 * MB);
    gprep<<<64, 256, 0, stream>>>(gso, Gb, Gt);
    prep_w_f<<<12, 256, 0, stream>>>(w, Wtf);
    cheb_fused<<<1024, 512, 0, stream>>>(x, Gb, Wtf, bias, out);
  }
}

// Round 13
// 203.022 us; speedup vs baseline: 1.1544x; 1.0429x over previous
//
#include <hip/hip_runtime.h>

typedef __attribute__((ext_vector_type(4))) float f32x4;
typedef __attribute__((ext_vector_type(8))) __bf16 bf16x8;
typedef __attribute__((ext_vector_type(4))) __bf16 bf16x4;

#define MFMA16(a, b, c) __builtin_amdgcn_mfma_f32_16x16x32_bf16((a), (b), (c), 0, 0, 0)

typedef const __attribute__((address_space(1))) void* gas1_t;
typedef __attribute__((address_space(3))) void* las3_t;
#define GLOAD16(gp, lp) __builtin_amdgcn_global_load_lds((gas1_t)(gp), (las3_t)(lp), 16, 0, 0)

__device__ __forceinline__ unsigned short bfbits(float f) {
  __bf16 b = (__bf16)f;
  return *reinterpret_cast<unsigned short*>(&b);
}

// ---- swizzled 8KB unit: logical [128 rows][64 B], phys = pair-row + slot-XOR ----
__device__ __forceinline__ int tile_addr(int row, int kb) {
  int s = (((row & 1) << 2) | (kb >> 4)) ^ ((row >> 1) & 7);
  return ((row >> 1) << 7) | (s << 4) | (kb & 15);
}
// inverse: phys p in [0,8192), 16B-aligned -> (row, kb)
__device__ __forceinline__ void tile_decode(int p, int& row, int& kb) {
  int pair = p >> 7;
  int sx = ((p >> 4) & 7) ^ (pair & 7);
  row = (pair << 1) | (sx >> 2);
  kb = (sx & 3) << 4;
}

// ---------------- K1: gprep (blocks 0..63) + prep_w3 (block 64) ----------------
// gprep: G -> Gb (bf16 row-major) + Gt (bf16 transposed)
// prep_w3: Wt[k][j][c]: k0 = W0 - W2, k1 = W1, k2 = 2*W2
__global__ __launch_bounds__(256)
void prep_all(const float* __restrict__ g, __bf16* __restrict__ Gb, __bf16* __restrict__ Gt,
              const float* __restrict__ w, __bf16* __restrict__ wt) {
  __shared__ __bf16 Lt[128 * 132];
  int tid = threadIdx.x;
  if (blockIdx.x < 64) {
    int rb = blockIdx.x >> 3, cb = blockIdx.x & 7;
    #pragma unroll
    for (int it = 0; it < 16; ++it) {
      int idx = it * 256 + tid;
      int r = idx >> 5, c4 = idx & 31;
      float4 v = *reinterpret_cast<const float4*>(g + (size_t)(rb * 128 + r) * 1024 + cb * 128 + c4 * 4);
      bf16x4 h;
      h[0] = (__bf16)v.x; h[1] = (__bf16)v.y; h[2] = (__bf16)v.z; h[3] = (__bf16)v.w;
      *reinterpret_cast<bf16x4*>(Gb + (size_t)(rb * 128 + r) * 1024 + cb * 128 + c4 * 4) = h;
      #pragma unroll
      for (int e = 0; e < 4; ++e) Lt[(c4 * 4 + e) * 132 + r] = h[e];
    }
    __syncthreads();
    #pragma unroll
    for (int it = 0; it < 8; ++it) {
      int idx = it * 256 + tid;
      int i = idx >> 4, ch = idx & 15;
      bf16x8 v;
      #pragma unroll
      for (int e = 0; e < 8; ++e) v[e] = Lt[i * 132 + ch * 8 + e];
      *reinterpret_cast<bf16x8*>(Gt + (size_t)(cb * 128 + i) * 1024 + rb * 128 + ch * 8) = v;
    }
  } else {
    for (int t = tid; t < 3072; t += 256) {
      int k = t >> 10, rem = t & 1023, j = rem >> 5, c = rem & 31;
      float wk = w[k * 1024 + c * 32 + j];
      float v;
      if (k == 0)      v = wk - w[2 * 1024 + c * 32 + j];
      else if (k == 1) v = wk;
      else             v = 2.0f * wk;
      wt[t] = (__bf16)v;
    }
  }
}

// ---------------- K2: gsq (blocks 0..63) + k0_transpose (blocks 64..4159) ----------------
// gsq: G2[h][i] = sum_k Gb[h][k] * Gt[i][k]   (independent of transpose -> co-scheduled,
// the 64 compute blocks hide under the transpose's memory traffic)
// k0_transpose: X0t[(b*64+t)*32 + c][i] = x[b][c][t][i]
__global__ __launch_bounds__(256, 2)
void gsq_trans(const __bf16* __restrict__ Gb, const __bf16* __restrict__ Gt,
               __bf16* __restrict__ G2b, const float* __restrict__ x,
               __bf16* __restrict__ X0t) {
  __shared__ char lds[32768];
  const int tid = threadIdx.x;
  if (blockIdx.x >= 64) {
    int n0 = (blockIdx.x - 64) * 8;
    #pragma unroll
    for (int r = 0; r < 8; ++r) {
      int n = n0 + r;
      int b = n >> 11, t = (n >> 5) & 63, c = n & 31;
      const float* src = x + (size_t)((b * 32 + c) * 64 + t) * 1024;
      float4 v = *reinterpret_cast<const float4*>(&src[tid * 4]);
      bf16x4 p;
      p[0] = (__bf16)v.x; p[1] = (__bf16)v.y; p[2] = (__bf16)v.z; p[3] = (__bf16)v.w;
      *reinterpret_cast<bf16x4*>(&X0t[(size_t)n * 1024 + tid * 4]) = p;
    }
    return;
  }

  const int lane = tid & 63, wid = tid >> 6;
  const int l15 = lane & 15, lg = lane >> 4;
  const int wr = wid >> 1, wc = wid & 1;
  const int hb = (blockIdx.x >> 3) * 128, ib = (blockIdx.x & 7) * 128;

  int r0, kb0, r1, kb1;
  tile_decode(tid * 16, r0, kb0);
  tile_decode(tid * 16 + 4096, r1, kb1);
  const char* A0 = (const char*)Gb + (size_t)hb * 2048;
  const char* B0 = (const char*)Gt + (size_t)ib * 2048;

  auto stage = [&](int buf, int kt) {
    char* base = lds + buf * 16384;
    size_t oA0 = (size_t)r0 * 2048 + kt * 64 + kb0;
    size_t oA1 = (size_t)r1 * 2048 + kt * 64 + kb1;
    GLOAD16(A0 + oA0, base + wid * 1024);
    GLOAD16(A0 + oA1, base + 4096 + wid * 1024);
    GLOAD16(B0 + oA0, base + 8192 + wid * 1024);
    GLOAD16(B0 + oA1, base + 12288 + wid * 1024);
  };

  const f32x4 zero = {0.f, 0.f, 0.f, 0.f};
  f32x4 acc[4][4];
  #pragma unroll
  for (int a = 0; a < 4; ++a)
    #pragma unroll
    for (int b = 0; b < 4; ++b) acc[a][b] = zero;

  stage(0, 0);
  __syncthreads();
  for (int kt = 0; kt < 32; ++kt) {
    int cur = kt & 1;
    if (kt < 31) stage(cur ^ 1, kt + 1);
    const char* A = lds + cur * 16384;
    const char* B = A + 8192;
    bf16x8 af[4], bf[4];
    #pragma unroll
    for (int i = 0; i < 4; ++i) {
      af[i] = *reinterpret_cast<const bf16x8*>(A + tile_addr(wr * 64 + i * 16 + l15, lg * 16));
      bf[i] = *reinterpret_cast<const bf16x8*>(B + tile_addr(wc * 64 + i * 16 + l15, lg * 16));
    }
    #pragma unroll
    for (int a = 0; a < 4; ++a)
      #pragma unroll
      for (int b = 0; b < 4; ++b) acc[a][b] = MFMA16(af[a], bf[b], acc[a][b]);
    __syncthreads();
  }
  #pragma unroll
  for (int a = 0; a < 4; ++a)
    #pragma unroll
    for (int b = 0; b < 4; ++b)
      #pragma unroll
      for (int q = 0; q < 4; ++q) {
        int h = hb + wr * 64 + a * 16 + lg * 4 + q;
        int i = ib + wc * 64 + b * 16 + l15;
        G2b[(size_t)h * 1024 + i] = (__bf16)acc[a][b][q];
      }
}

// ---------------- main: R12-verified (counted-vmcnt 3-buffer, no lgkm pin) ----------------
__global__ __launch_bounds__(256, 2)
void cheb_main(const __bf16* __restrict__ Gb, const __bf16* __restrict__ G2b,
               const __bf16* __restrict__ X0t, const __bf16* __restrict__ Wt,
               const float* __restrict__ bias, float* __restrict__ out)
{
  __shared__ char lds[73728];
  // K-loop: 3 buffers @0/24576/49152, each {A1 8K | A2 8K | B 8K}
  // epilogue (reuse): X0tile @0 (32K), b1 @32768 (8K), b2 @40960 (8K)

  const int tid = threadIdx.x;
  const int lane = tid & 63, wid = tid >> 6;
  const int l15 = lane & 15, lg = lane >> 4;
  const int wr = wid >> 1, wc = wid & 1;

  const int ht = blockIdx.x & 7;        // XCD-resident G/G2 panel
  const int nt = blockIdx.x >> 3;

  int r0, kb0, r1, kb1;
  tile_decode(tid * 16, r0, kb0);
  tile_decode(tid * 16 + 4096, r1, kb1);

  const char* A1g = (const char*)Gb + (size_t)ht * 128 * 2048;
  const char* A2g = (const char*)G2b + (size_t)ht * 128 * 2048;
  const char* Bg  = (const char*)X0t + (size_t)nt * 128 * 2048;

  const int widb = wid * 1024;

  auto stage = [&](char* base, int kt) {
    size_t o0 = (size_t)r0 * 2048 + kt * 64 + kb0;
    size_t o1 = (size_t)r1 * 2048 + kt * 64 + kb1;
    GLOAD16(A1g + o0, base + widb);
    GLOAD16(A1g + o1, base + 4096 + widb);
    GLOAD16(A2g + o0, base + 8192 + widb);
    GLOAD16(A2g + o1, base + 12288 + widb);
    GLOAD16(Bg + o0, base + 16384 + widb);
    GLOAD16(Bg + o1, base + 20480 + widb);
  };

  // per-thread frag offsets within a buffer
  const int lgk = lg * 16;
  int offA[4], offB[4];
  #pragma unroll
  for (int a = 0; a < 4; ++a) offA[a] = tile_addr(wr * 64 + a * 16 + l15, lgk);
  #pragma unroll
  for (int b = 0; b < 4; ++b) offB[b] = 16384 + tile_addr(wc * 64 + b * 16 + l15, lgk);

  const f32x4 zero = {0.f, 0.f, 0.f, 0.f};
  f32x4 acc1[4][4], acc2[4][4];
  #pragma unroll
  for (int a = 0; a < 4; ++a)
    #pragma unroll
    for (int b = 0; b < 4; ++b) { acc1[a][b] = zero; acc2[a][b] = zero; }

  char* p0 = lds;
  char* p1 = lds + 24576;
  char* p2 = lds + 49152;

  // prologue: stage tiles 0,1; wait tile 0 only (6 of 12 outstanding)
  stage(p0, 0);
  stage(p1, 1);
  asm volatile("s_waitcnt vmcnt(6)" ::: "memory");
  __builtin_amdgcn_sched_barrier(0);
  __builtin_amdgcn_s_barrier();
  __builtin_amdgcn_sched_barrier(0);

  for (int t = 0; t < 32; ++t) {
    bf16x8 a1[4], a2[4], bf[4];
    #pragma unroll
    for (int i = 0; i < 4; ++i) {
      bf[i] = *reinterpret_cast<const bf16x8*>(p0 + offB[i]);
      a1[i] = *reinterpret_cast<const bf16x8*>(p0 + offA[i]);
      a2[i] = *reinterpret_cast<const bf16x8*>(p0 + 8192 + offA[i]);
    }
    if (t < 30) stage(p2, t + 2);
    // compiler-inserted fine-grained lgkmcnt interleaves MFMAs with read returns
    __builtin_amdgcn_s_setprio(1);
    #pragma unroll
    for (int a = 0; a < 4; ++a)
      #pragma unroll
      for (int b = 0; b < 4; ++b) {
        acc1[a][b] = MFMA16(a1[a], bf[b], acc1[a][b]);
        acc2[a][b] = MFMA16(a2[a], bf[b], acc2[a][b]);
      }
    __builtin_amdgcn_s_setprio(0);
    if (t < 30) {
      asm volatile("s_waitcnt vmcnt(6)" ::: "memory");
    } else if (t == 30) {
      asm volatile("s_waitcnt vmcnt(0)" ::: "memory");
    }
    if (t < 31) {
      __builtin_amdgcn_sched_barrier(0);
      __builtin_amdgcn_s_barrier();
      __builtin_amdgcn_sched_barrier(0);
    }
    char* tp = p0; p0 = p1; p1 = p2; p2 = tp;
  }

  __syncthreads();

  // ---- epilogue (R4/R9-verified 4-wave version) ----
  // stage X0tile: [128 n-rows][256 B of h-cols], linear, 32KB @0
  #pragma unroll
  for (int i = 0; i < 8; ++i) {
    int pbase = i * 4096 + widb;              // wave-uniform dest (HW adds lane*16)
    int pb = pbase + lane * 16;
    int prow = pb >> 8, pcol = pb & 255;
    GLOAD16((const char*)X0t + (size_t)(nt * 128 + prow) * 2048 + ht * 256 + pcol,
            lds + pbase);
  }

  bf16x8 wf[3][2];
  #pragma unroll
  for (int s = 0; s < 3; ++s)
    #pragma unroll
    for (int jf = 0; jf < 2; ++jf)
      wf[s][jf] = *reinterpret_cast<const bf16x8*>(Wt + s * 1024 + (jf * 16 + l15) * 32 + lg * 8);
  float bv[2] = {bias[l15], bias[16 + l15]};

  #pragma unroll
  for (int bt = 0; bt < 4; ++bt) {
    if (bt > 0) __syncthreads();              // prev bt's reads done before overwrite
    // bounce this bt's acc columns -> b1/b2 as [128 h][32 c] swizzled tiles
    if (wc == (bt >> 1)) {
      #pragma unroll
      for (int a = 0; a < 4; ++a)
        #pragma unroll
        for (int bsel = 0; bsel < 2; ++bsel) {
          int b = ((bt & 1) << 1) | bsel;
          int cb = (bsel * 16 + l15) * 2;
          #pragma unroll
          for (int q = 0; q < 4; ++q) {
            int h = wr * 64 + a * 16 + lg * 4 + q;
            *reinterpret_cast<unsigned short*>(lds + 32768 + tile_addr(h, cb)) = bfbits(acc1[a][b][q]);
            *reinterpret_cast<unsigned short*>(lds + 40960 + tile_addr(h, cb)) = bfbits(acc2[a][b][q]);
          }
        }
    }
    __syncthreads();

    // D[h][j] = bias + X0*(W0-W2) + Y1*W1 + Y2*(2W2); wave owns h-slice wid*32
    f32x4 D[2][2];
    #pragma unroll
    for (int mf = 0; mf < 2; ++mf) {
      D[mf][0] = (f32x4){bv[0], bv[0], bv[0], bv[0]};
      D[mf][1] = (f32x4){bv[1], bv[1], bv[1], bv[1]};
    }
    #pragma unroll
    for (int mf = 0; mf < 2; ++mf) {
      int hx = wid * 32 + mf * 16 + l15;
      bf16x8 s0;
      #pragma unroll
      for (int i2 = 0; i2 < 8; ++i2)
        ((unsigned short*)&s0)[i2] =
            *reinterpret_cast<const unsigned short*>(lds + (bt * 32 + lg * 8 + i2) * 256 + hx * 2);
      bf16x8 s1 = *reinterpret_cast<const bf16x8*>(lds + 32768 + tile_addr(hx, lg * 16));
      bf16x8 s2 = *reinterpret_cast<const bf16x8*>(lds + 40960 + tile_addr(hx, lg * 16));
      #pragma unroll
      for (int jf = 0; jf < 2; ++jf) {
        D[mf][jf] = MFMA16(s0, wf[0][jf], D[mf][jf]);
        D[mf][jf] = MFMA16(s1, wf[1][jf], D[mf][jf]);
        D[mf][jf] = MFMA16(s2, wf[2][jf], D[mf][jf]);
      }
    }
    size_t ob = (size_t)(nt * 4 + bt) * 32768 + (size_t)(ht * 128 + wid * 32) * 32;
    #pragma unroll
    for (int mf = 0; mf < 2; ++mf)
      #pragma unroll
      for (int jf = 0; jf < 2; ++jf)
        #pragma unroll
        for (int q = 0; q < 4; ++q)
          out[ob + (size_t)(mf * 16 + lg * 4 + q) * 32 + jf * 16 + l15] = D[mf][jf][q];
  }
}

// ---------------- fallback (R1, proven): used if ws too small ----------------
__device__ __forceinline__ int swz_f(int c, int i) {
  return (c << 10) + (i ^ ((c & 7) << 3));
}
__global__ __launch_bounds__(256)
void gprep_f(const float* __restrict__ g, __bf16* __restrict__ Gb) {
  int i = (blockIdx.x * 256 + threadIdx.x) * 4;
  float4 v = *reinterpret_cast<const float4*>(g + i);
  bf16x4 h;
  h[0] = (__bf16)v.x; h[1] = (__bf16)v.y; h[2] = (__bf16)v.z; h[3] = (__bf16)v.w;
  *reinterpret_cast<bf16x4*>(Gb + i) = h;
}
__global__ void prep_w_f(const float* __restrict__ w, __bf16* __restrict__ wt) {
  int tid = blockIdx.x * 256 + threadIdx.x;
  if (tid < 3 * 32 * 32) {
    int k = tid >> 10, rem = tid & 1023;
    int j = rem >> 5, c = rem & 31;
    float s = (k == 1) ? 0.5f : 1.0f;
    wt[tid] = (__bf16)(w[(k * 32 + c) * 32 + j] * s);
  }
}
__global__ __launch_bounds__(512, 2)
void cheb_fused(const float* __restrict__ x, const __bf16* __restrict__ Gb,
                const __bf16* __restrict__ Wt, const float* __restrict__ bias,
                float* __restrict__ out)
{
  __shared__ __bf16 ldsX[32 * 1024];
  __shared__ __bf16 ldsY[32 * 1024];
  const int wg = blockIdx.x;
  const int b = wg >> 6, t = wg & 63;
  const int tid = threadIdx.x;
  const int lane = tid & 63;
  const int wid = tid >> 6;
  const int l15 = lane & 15;
  const int lg = lane >> 4;
  {
    const int c = tid >> 4;
    const int seg = tid & 15;
    const float* xr = x + (size_t)((b * 32 + c) * 64 + t) * 1024;
    #pragma unroll
    for (int g = 0; g < 8; ++g) {
      int i0 = g * 128 + seg * 8;
      float4 v0 = *reinterpret_cast<const float4*>(xr + i0);
      float4 v1 = *reinterpret_cast<const float4*>(xr + i0 + 4);
      bf16x8 h;
      h[0] = (__bf16)v0.x; h[1] = (__bf16)v0.y; h[2] = (__bf16)v0.z; h[3] = (__bf16)v0.w;
      h[4] = (__bf16)v1.x; h[5] = (__bf16)v1.y; h[6] = (__bf16)v1.z; h[7] = (__bf16)v1.w;
      *reinterpret_cast<bf16x8*>(&ldsX[swz_f(c, i0)]) = h;
    }
  }
  __syncthreads();
  const f32x4 zero = {0.f, 0.f, 0.f, 0.f};
  f32x4 acc[8][2];
  #pragma unroll
  for (int r = 0; r < 8; ++r) { acc[r][0] = zero; acc[r][1] = zero; }
  const __bf16* Ga = Gb + (size_t)(wid * 128 + l15) * 1024 + lg * 8;
  #pragma unroll 2
  for (int k = 0; k < 1024; k += 32) {
    bf16x8 bf0 = *reinterpret_cast<const bf16x8*>(&ldsX[swz_f(l15, k + lg * 8)]);
    bf16x8 bf1 = *reinterpret_cast<const bf16x8*>(&ldsX[swz_f(16 + l15, k + lg * 8)]);
    bf16x8 af[8];
    #pragma unroll
    for (int r = 0; r < 8; ++r)
      af[r] = *reinterpret_cast<const bf16x8*>(Ga + r * 16 * 1024 + k);
    #pragma unroll
    for (int r = 0; r < 8; ++r) {
      acc[r][0] = MFMA16(af[r], bf0, acc[r][0]);
      acc[r][1] = MFMA16(af[r], bf1, acc[r][1]);
    }
  }
  #pragma unroll
  for (int r = 0; r < 8; ++r) {
    int hb = wid * 128 + r * 16 + lg * 4;
    #pragma unroll
    for (int cf = 0; cf < 2; ++cf) {
      int c = cf * 16 + l15;
      bf16x4 p;
      #pragma unroll
      for (int q = 0; q < 4; ++q) p[q] = (__bf16)(2.0f * acc[r][cf][q]);
      *reinterpret_cast<bf16x4*>(&ldsY[swz_f(c, hb)]) = p;
    }
  }
  __syncthreads();
  #pragma unroll
  for (int r = 0; r < 8; ++r) {
    int hb = wid * 128 + r * 16 + lg * 4;
    #pragma unroll
    for (int cf = 0; cf < 2; ++cf) {
      int c = cf * 16 + l15;
      bf16x4 xv = *reinterpret_cast<const bf16x4*>(&ldsX[swz_f(c, hb)]);
      f32x4 a;
      #pragma unroll
      for (int q = 0; q < 4; ++q) a[q] = -(float)xv[q];
      acc[r][cf] = a;
    }
  }
  #pragma unroll 2
  for (int k = 0; k < 1024; k += 32) {
    bf16x8 bf0 = *reinterpret_cast<const bf16x8*>(&ldsY[swz_f(l15, k + lg * 8)]);
    bf16x8 bf1 = *reinterpret_cast<const bf16x8*>(&ldsY[swz_f(16 + l15, k + lg * 8)]);
    bf16x8 af[8];
    #pragma unroll
    for (int r = 0; r < 8; ++r)
      af[r] = *reinterpret_cast<const bf16x8*>(Ga + r * 16 * 1024 + k);
    #pragma unroll
    for (int r = 0; r < 8; ++r) {
      acc[r][0] = MFMA16(af[r], bf0, acc[r][0]);
      acc[r][1] = MFMA16(af[r], bf1, acc[r][1]);
    }
  }
  f32x4 oacc[8][2];
  {
    float b0 = bias[l15], b1 = bias[16 + l15];
    f32x4 v0 = {b0, b0, b0, b0}, v1 = {b1, b1, b1, b1};
    #pragma unroll
    for (int r = 0; r < 8; ++r) { oacc[r][0] = v0; oacc[r][1] = v1; }
  }
  auto contrib = [&](const __bf16* lds, const __bf16* wtk) {
    bf16x8 w0 = *reinterpret_cast<const bf16x8*>(wtk + l15 * 32 + lg * 8);
    bf16x8 w1 = *reinterpret_cast<const bf16x8*>(wtk + (16 + l15) * 32 + lg * 8);
    #pragma unroll
    for (int r = 0; r < 8; ++r) {
      int h = wid * 128 + r * 16 + l15;
      bf16x8 af;
      #pragma unroll
      for (int j = 0; j < 8; ++j) af[j] = lds[swz_f(lg * 8 + j, h)];
      oacc[r][0] = MFMA16(af, w0, oacc[r][0]);
      oacc[r][1] = MFMA16(af, w1, oacc[r][1]);
    }
  };
  contrib(ldsX, Wt);
  #pragma unroll
  for (int r = 0; r < 8; ++r) {
    int hb = wid * 128 + r * 16 + lg * 4;
    #pragma unroll
    for (int cf = 0; cf < 2; ++cf) {
      int c = cf * 16 + l15;
      bf16x4 p;
      #pragma unroll
      for (int q = 0; q < 4; ++q) p[q] = (__bf16)acc[r][cf][q];
      *reinterpret_cast<bf16x4*>(&ldsX[swz_f(c, hb)]) = p;
    }
  }
  contrib(ldsY, Wt + 1024);
  contrib(ldsX, Wt + 2048);
  float* ob = out + (size_t)wg * 32768;
  #pragma unroll
  for (int r = 0; r < 8; ++r) {
    int hb = wid * 128 + r * 16 + lg * 4;
    #pragma unroll
    for (int q = 0; q < 4; ++q) {
      ob[(hb + q) * 32 + l15] = oacc[r][0][q];
      ob[(hb + q) * 32 + 16 + l15] = oacc[r][1][q];
    }
  }
}

// ---------------- launch ----------------
extern "C" void kernel_launch(void* const* d_in, const int* in_sizes, int n_in,
                              void* d_out, int out_size, void* d_ws, size_t ws_size,
                              hipStream_t stream) {
  const float* x    = (const float*)d_in[0];
  const float* gso  = (const float*)d_in[1];
  const float* w    = (const float*)d_in[2];
  const float* bias = (const float*)d_in[3];
  float* out = (float*)d_out;

  char* ws = (char*)d_ws;
  const size_t MB = 1024 * 1024;
  __bf16* Gb  = (__bf16*)(ws);                // 2 MB
  __bf16* Gt  = (__bf16*)(ws + 2 * MB);       // 2 MB
  __bf16* G2b = (__bf16*)(ws + 4 * MB);       // 2 MB
  __bf16* Wt  = (__bf16*)(ws + 6 * MB);       // 8 KB
  __bf16* X0t = (__bf16*)(ws + 8 * MB);       // 64 MB
  const size_t need = 8 * MB + 64 * MB;

  if (ws_size >= need) {
    prep_all<<<65, 256, 0, stream>>>(gso, Gb, Gt, w, Wt);
    gsq_trans<<<4160, 256, 0, stream>>>(Gb, Gt, G2b, x, X0t);
    cheb_main<<<2048, 256, 0, stream>>>(Gb, G2b, X0t, Wt, bias, out);
  } else {
    __bf16* Wtf = (__bf16*)(ws + 6 * MB);
    gprep_f<<<1024, 256, 0, stream>>>(gso, Gb);
    prep_w_f<<<12, 256, 0, stream>>>(w, Wtf);
    cheb_fused<<<1024, 512, 0, stream>>>(x, Gb, Wtf, bias, out);
  }
}